// Round 8
// baseline (405.953 us; speedup 1.0000x reference)
//
#include <hip/hip_runtime.h>
#include <hip/hip_bf16.h>
#include <cstdint>
#include <cstddef>

// Shapes fixed: B=64, N=1024, D=512, S=16, 3 iterations.
// Algebra: logits = sn·W'·x^T with W' = scale·Wq^T·Wk  (k never materialized)
//          updates^T = vT_b @ attn_b^T  (vT stored transposed per batch)

typedef __bf16 bf16x8 __attribute__((ext_vector_type(8)));
typedef float f32x4 __attribute__((ext_vector_type(4)));

__device__ __forceinline__ float bf2f(unsigned int u) {
  union { unsigned int i; float f; } v; v.i = u << 16; return v.f;
}
__device__ __forceinline__ unsigned short f2bf(float x) {
  __hip_bfloat16 h = __float2bfloat16(x);
  unsigned short u;
  __builtin_memcpy(&u, &h, 2);
  return u;
}

#define GLD16(gp, lp)                                                       \
  __builtin_amdgcn_global_load_lds(                                         \
      (const __attribute__((address_space(1))) void*)(gp),                  \
      (__attribute__((address_space(3))) void*)(lp), 16, 0, 0)

// ---------------- merged weight prep / init (segmented grid) ----------------

__global__ void wprep_k(const float* __restrict__ Wv, const float* __restrict__ w1,
                        const float* __restrict__ w2, const float* __restrict__ wih,
                        const float* __restrict__ whh, const float* __restrict__ bih,
                        const float* __restrict__ bhh, const float* __restrict__ mu,
                        const float* __restrict__ ls, const float* __restrict__ noise,
                        unsigned short* __restrict__ wv_bf, unsigned short* __restrict__ w1_bf,
                        unsigned short* __restrict__ w2_bf, unsigned short* __restrict__ wcat,
                        float* __restrict__ bcat, float* __restrict__ slots) {
  int blk = blockIdx.x, t = threadIdx.x;
  if (blk < 1024) {
    int i = blk * 256 + t; wv_bf[i] = f2bf(Wv[i]);
  } else if (blk < 2048) {
    int i = (blk - 1024) * 256 + t; w1_bf[i] = f2bf(w1[i]);
  } else if (blk < 3072) {
    int i = (blk - 2048) * 256 + t; w2_bf[i] = f2bf(w2[i]);
  } else if (blk < 11264) {
    int i = (blk - 3072) * 256 + t;  // 2M
    int j = i >> 10, k = i & 1023;
    float v;
    if (j < 1024)      v = (k < 512) ? wih[j * 512 + k] : whh[j * 512 + (k - 512)];
    else if (j < 1536) v = (k < 512) ? wih[j * 512 + k] : 0.0f;
    else               v = (k < 512) ? 0.0f : whh[(j - 512) * 512 + (k - 512)];
    wcat[i] = f2bf(v);
  } else if (blk < 11272) {
    int j = (blk - 11264) * 256 + t;  // 2048
    float v;
    if (j < 1024)      v = bih[j] + bhh[j];
    else if (j < 1536) v = bih[j];
    else               v = bhh[j - 512];
    bcat[j] = v;
  } else {
    int i = (blk - 11272) * 256 + t;  // 524288
    int d = i & 511;
    slots[i] = mu[d] + expf(ls[d]) * noise[i];
  }
}

// transpose + cast both Wq, Wk: grid (16,16,2)
__global__ __launch_bounds__(256) void tcast2_k(const float* __restrict__ Wq,
                                                const float* __restrict__ Wk,
                                                unsigned short* __restrict__ wqT,
                                                unsigned short* __restrict__ wkT) {
  __shared__ float tt[32][33];
  const float* in = blockIdx.z ? Wk : Wq;
  unsigned short* out = blockIdx.z ? wkT : wqT;
  int c0 = blockIdx.x << 5, r0 = blockIdx.y << 5;
  int tx = threadIdx.x & 31, ty = threadIdx.x >> 5;
  #pragma unroll
  for (int i = 0; i < 4; ++i)
    tt[ty + 8 * i][tx] = in[(size_t)(r0 + ty + 8 * i) * 512 + c0 + tx];
  __syncthreads();
  #pragma unroll
  for (int i = 0; i < 4; ++i)
    out[(size_t)(c0 + ty + 8 * i) * 512 + r0 + tx] = f2bf(tt[tx][ty + 8 * i]);
}

// ---------------- layernorm inputs (wave per row, D=512) ----------------

__global__ __launch_bounds__(256) void ln_rows_k(
    const float* __restrict__ in, const float* __restrict__ g, const float* __restrict__ b,
    unsigned short* __restrict__ out, int rows) {
  int w = threadIdx.x >> 6, lane = threadIdx.x & 63;
  int row = (blockIdx.x << 2) + w;
  if (row >= rows) return;
  const float4* rp = reinterpret_cast<const float4*>(in + (size_t)row * 512);
  float4 v0 = rp[lane], v1 = rp[lane + 64];
  float s = v0.x + v0.y + v0.z + v0.w + v1.x + v1.y + v1.z + v1.w;
  float q = v0.x*v0.x + v0.y*v0.y + v0.z*v0.z + v0.w*v0.w
          + v1.x*v1.x + v1.y*v1.y + v1.z*v1.z + v1.w*v1.w;
  #pragma unroll
  for (int o = 32; o > 0; o >>= 1) { s += __shfl_xor(s, o); q += __shfl_xor(q, o); }
  float m = s * (1.0f / 512.0f);
  float rstd = rsqrtf(q * (1.0f / 512.0f) - m * m + 1e-8f);
  const float4* gp = reinterpret_cast<const float4*>(g);
  const float4* bp = reinterpret_cast<const float4*>(b);
  float4 g0 = gp[lane], g1 = gp[lane + 64];
  float4 b0 = bp[lane], b1 = bp[lane + 64];
  ushort4 o0, o1;
  o0.x = f2bf((v0.x - m) * rstd * g0.x + b0.x);
  o0.y = f2bf((v0.y - m) * rstd * g0.y + b0.y);
  o0.z = f2bf((v0.z - m) * rstd * g0.z + b0.z);
  o0.w = f2bf((v0.w - m) * rstd * g0.w + b0.w);
  o1.x = f2bf((v1.x - m) * rstd * g1.x + b1.x);
  o1.y = f2bf((v1.y - m) * rstd * g1.y + b1.y);
  o1.z = f2bf((v1.z - m) * rstd * g1.z + b1.z);
  o1.w = f2bf((v1.w - m) * rstd * g1.w + b1.w);
  ushort4* op = reinterpret_cast<ushort4*>(out + (size_t)row * 512);
  op[lane] = o0; op[lane + 64] = o1;
}

// GRU (fused-gates layout) + LN: gates[row][2048] = [rsum, zsum, i_n, h_n]
__global__ __launch_bounds__(256) void gru_ln_k(
    const float* __restrict__ gates, const float* __restrict__ hp,
    const float* __restrict__ g, const float* __restrict__ b,
    float* __restrict__ sgru, unsigned short* __restrict__ lnm) {
  int w = threadIdx.x >> 6, lane = threadIdx.x & 63;
  int row = (blockIdx.x << 2) + w;
  size_t gb = (size_t)row * 2048 + (lane << 3);
  size_t hb = (size_t)row * 512 + (lane << 3);
  float rs[8], zs[8], in_[8], hn[8], hv[8], y[8];
  #pragma unroll
  for (int c = 0; c < 2; ++c) {
    *reinterpret_cast<float4*>(rs + 4*c)  = *reinterpret_cast<const float4*>(gates + gb + 4*c);
    *reinterpret_cast<float4*>(zs + 4*c)  = *reinterpret_cast<const float4*>(gates + gb + 512 + 4*c);
    *reinterpret_cast<float4*>(in_ + 4*c) = *reinterpret_cast<const float4*>(gates + gb + 1024 + 4*c);
    *reinterpret_cast<float4*>(hn + 4*c)  = *reinterpret_cast<const float4*>(gates + gb + 1536 + 4*c);
    *reinterpret_cast<float4*>(hv + 4*c)  = *reinterpret_cast<const float4*>(hp + hb + 4*c);
  }
  float s = 0.f, q = 0.f;
  #pragma unroll
  for (int j = 0; j < 8; ++j) {
    float r = 1.0f / (1.0f + expf(-rs[j]));
    float z = 1.0f / (1.0f + expf(-zs[j]));
    float n = tanhf(in_[j] + r * hn[j]);
    float h = (1.0f - z) * n + z * hv[j];
    y[j] = h; s += h; q += h * h;
  }
  #pragma unroll
  for (int o = 32; o > 0; o >>= 1) { s += __shfl_xor(s, o); q += __shfl_xor(q, o); }
  float m = s * (1.0f / 512.0f);
  float rstd = rsqrtf(q * (1.0f / 512.0f) - m * m + 1e-8f);
  const float* gg = g + (lane << 3);
  const float* bb = b + (lane << 3);
  #pragma unroll
  for (int c = 0; c < 2; ++c)
    *reinterpret_cast<float4*>(sgru + hb + 4*c) = *reinterpret_cast<const float4*>(y + 4*c);
  uint4 o4;
  unsigned int p[8];
  #pragma unroll
  for (int j = 0; j < 8; ++j) p[j] = f2bf((y[j] - m) * rstd * gg[j] + bb[j]);
  o4.x = p[0] | (p[1] << 16); o4.y = p[2] | (p[3] << 16);
  o4.z = p[4] | (p[5] << 16); o4.w = p[6] | (p[7] << 16);
  *reinterpret_cast<uint4*>(lnm + hb) = o4;
}

// ---------------- MFMA GEMM 128x128: C[M,N] = A[M,K] @ W[N,K]^T ----------------
// 4 waves of 64x64, gload_lds 2-buffer, XCD swizzle. M%128==0, N%128==0, K%32==0.

template<int BIAS, int RELU, int ADDSRC, int OUTBF16>
__global__ __launch_bounds__(256) void gemm_bt(
    const unsigned short* __restrict__ A, const unsigned short* __restrict__ W,
    const float* __restrict__ bias, const float* __restrict__ addsrc,
    void* __restrict__ Cout, int M, int N, int K) {
  __shared__ unsigned short sA[2][4096];  // [128][32] linear
  __shared__ unsigned short sB[2][4096];
  const int tid = threadIdx.x;
  const int lane = tid & 63, w = tid >> 6;

  int nwg = gridDim.x * gridDim.y;
  int flat = blockIdx.y * gridDim.x + blockIdx.x;
  if ((nwg & 7) == 0) { int c = nwg >> 3; flat = (flat & 7) * c + (flat >> 3); }
  const int row0 = (flat / gridDim.x) << 7;
  const int col0 = (flat % gridDim.x) << 7;

  const int wm = (w >> 1) << 6, wn = (w & 1) << 6;
  const int lrow = lane & 15, kt = (lane >> 4) << 3;
  const int srow = lane >> 2, scol = (lane & 3) << 3;

  f32x4 acc[4][4];
  #pragma unroll
  for (int m = 0; m < 4; ++m)
    #pragma unroll
    for (int n = 0; n < 4; ++n) acc[m][n] = f32x4{0.f, 0.f, 0.f, 0.f};

  auto stage = [&](int buf, int k0) {
    #pragma unroll
    for (int i = 0; i < 2; ++i) {
      int ii = w * 2 + i;
      int r = (ii << 4) + srow;
      GLD16(A + (size_t)(row0 + r) * K + k0 + scol, &sA[buf][ii * 512]);
      GLD16(W + (size_t)(col0 + r) * K + k0 + scol, &sB[buf][ii * 512]);
    }
  };

  stage(0, 0);
  const int nt = K >> 5;
  int cur = 0;
  for (int t = 0; t < nt; ++t) {
    __syncthreads();
    if (t + 1 < nt) stage(cur ^ 1, (t + 1) << 5);
    bf16x8 af[4], bfv[4];
    #pragma unroll
    for (int m = 0; m < 4; ++m)
      af[m] = *reinterpret_cast<const bf16x8*>(&sA[cur][(wm + m * 16 + lrow) * 32 + kt]);
    #pragma unroll
    for (int n = 0; n < 4; ++n)
      bfv[n] = *reinterpret_cast<const bf16x8*>(&sB[cur][(wn + n * 16 + lrow) * 32 + kt]);
    #pragma unroll
    for (int m = 0; m < 4; ++m)
      #pragma unroll
      for (int n = 0; n < 4; ++n)
        acc[m][n] = __builtin_amdgcn_mfma_f32_16x16x32_bf16(af[m], bfv[n], acc[m][n], 0, 0, 0);
    cur ^= 1;
  }

  const int rb = (lane >> 4) << 2;  // C/D: col = lane&15, row = (lane>>4)*4 + reg
  #pragma unroll
  for (int m = 0; m < 4; ++m) {
    #pragma unroll
    for (int n = 0; n < 4; ++n) {
      int col = col0 + wn + n * 16 + lrow;
      float bv = BIAS ? bias[col] : 0.0f;
      #pragma unroll
      for (int r = 0; r < 4; ++r) {
        int row = row0 + wm + m * 16 + rb + r;
        float v = acc[m][n][r] + bv;
        if (ADDSRC) v += addsrc[(size_t)row * N + col];
        if (RELU) v = fmaxf(v, 0.0f);
        if (OUTBF16) ((unsigned short*)Cout)[(size_t)row * N + col] = f2bf(v);
        else ((float*)Cout)[(size_t)row * N + col] = v;
      }
    }
  }
}

// ---------------- gemm_vt: vT[b][d][n] = (x @ Wv^T) transposed per b ----------------

__global__ __launch_bounds__(256) void gemm_vt(
    const unsigned short* __restrict__ A, const unsigned short* __restrict__ W,
    unsigned short* __restrict__ vT) {
  __shared__ unsigned short sA[2][4096];  // [128][32]
  __shared__ unsigned short sB[2][4096];
  const int tid = threadIdx.x;
  const int lane = tid & 63, w = tid >> 6;

  int flat = blockIdx.y * 4 + blockIdx.x;
  { int c = 2048 >> 3; flat = (flat & 7) * c + (flat >> 3); }
  const int row0 = (flat >> 2) << 7;
  const int col0 = (flat & 3) << 7;
  const int K = 512;

  const int wm = (w >> 1) << 6, wn = (w & 1) << 6;
  const int lrow = lane & 15, kt = (lane >> 4) << 3;
  const int srow = lane >> 2, scol = (lane & 3) << 3;

  f32x4 acc[4][4];
  #pragma unroll
  for (int m = 0; m < 4; ++m)
    #pragma unroll
    for (int n = 0; n < 4; ++n) acc[m][n] = f32x4{0.f, 0.f, 0.f, 0.f};

  auto stage = [&](int buf, int k0) {
    #pragma unroll
    for (int i = 0; i < 2; ++i) {
      int ii = w * 2 + i;
      int r = (ii << 4) + srow;
      GLD16(A + (size_t)(row0 + r) * K + k0 + scol, &sA[buf][ii * 512]);
      GLD16(W + (size_t)(col0 + r) * K + k0 + scol, &sB[buf][ii * 512]);
    }
  };

  stage(0, 0);
  int cur = 0;
  for (int t = 0; t < 16; ++t) {
    __syncthreads();
    if (t + 1 < 16) stage(cur ^ 1, (t + 1) << 5);
    bf16x8 af[4], bfv[4];
    #pragma unroll
    for (int m = 0; m < 4; ++m)
      af[m] = *reinterpret_cast<const bf16x8*>(&sA[cur][(wm + m * 16 + lrow) * 32 + kt]);
    #pragma unroll
    for (int n = 0; n < 4; ++n)
      bfv[n] = *reinterpret_cast<const bf16x8*>(&sB[cur][(wn + n * 16 + lrow) * 32 + kt]);
    #pragma unroll
    for (int m = 0; m < 4; ++m)
      #pragma unroll
      for (int n = 0; n < 4; ++n)
        acc[m][n] = __builtin_amdgcn_mfma_f32_16x16x32_bf16(af[m], bfv[n], acc[m][n], 0, 0, 0);
    cur ^= 1;
  }

  const int rb = (lane >> 4) << 2;
  const int b = row0 >> 10;
  const int n0 = row0 & 1023;
  unsigned short* vb = vT + ((size_t)b << 19);
  #pragma unroll
  for (int m = 0; m < 4; ++m) {
    #pragma unroll
    for (int n = 0; n < 4; ++n) {
      int col = col0 + wn + n * 16 + lrow;          // d
      int nn = n0 + wm + m * 16 + rb;               // n (4 consecutive)
      ushort4 o;
      o.x = f2bf(acc[m][n][0]); o.y = f2bf(acc[m][n][1]);
      o.z = f2bf(acc[m][n][2]); o.w = f2bf(acc[m][n][3]);
      *reinterpret_cast<ushort4*>(vb + (size_t)col * 1024 + nn) = o;
    }
  }
}

// ---------------- q2ln: LN(slots_b) in LDS, then q2 = sn @ W' tile ----------------

__global__ __launch_bounds__(256) void q2ln_k(
    const float* __restrict__ slots, const float* __restrict__ g, const float* __restrict__ b,
    const unsigned short* __restrict__ wpt, unsigned short* __restrict__ q2,
    unsigned short* __restrict__ A2) {
  __shared__ unsigned short s_sn[16 * 520];  // [16][520]
  __shared__ unsigned short sB[2][4096];     // [128][32]
  const int b_ = blockIdx.y, ct = blockIdx.x;
  const int lane = threadIdx.x & 63, w = threadIdx.x >> 6;
  const int lrow = lane & 15, kt = (lane >> 4) << 3;
  const int srow = lane >> 2, scol = (lane & 3) << 3;

  const float4* gp = reinterpret_cast<const float4*>(g);
  const float4* bp = reinterpret_cast<const float4*>(b);
  float4 g0 = gp[lane], g1 = gp[lane + 64];
  float4 b0 = bp[lane], b1 = bp[lane + 64];
  #pragma unroll
  for (int rr = 0; rr < 4; ++rr) {
    int r = w * 4 + rr;
    const float4* rp = reinterpret_cast<const float4*>(slots + (size_t)(b_ * 16 + r) * 512);
    float4 v0 = rp[lane], v1 = rp[lane + 64];
    float s = v0.x + v0.y + v0.z + v0.w + v1.x + v1.y + v1.z + v1.w;
    float q = v0.x*v0.x + v0.y*v0.y + v0.z*v0.z + v0.w*v0.w
            + v1.x*v1.x + v1.y*v1.y + v1.z*v1.z + v1.w*v1.w;
    #pragma unroll
    for (int o = 32; o > 0; o >>= 1) { s += __shfl_xor(s, o); q += __shfl_xor(q, o); }
    float m = s * (1.0f / 512.0f);
    float rstd = rsqrtf(q * (1.0f / 512.0f) - m * m + 1e-8f);
    ushort4 o0, o1;
    o0.x = f2bf((v0.x - m) * rstd * g0.x + b0.x);
    o0.y = f2bf((v0.y - m) * rstd * g0.y + b0.y);
    o0.z = f2bf((v0.z - m) * rstd * g0.z + b0.z);
    o0.w = f2bf((v0.w - m) * rstd * g0.w + b0.w);
    o1.x = f2bf((v1.x - m) * rstd * g1.x + b1.x);
    o1.y = f2bf((v1.y - m) * rstd * g1.y + b1.y);
    o1.z = f2bf((v1.z - m) * rstd * g1.z + b1.z);
    o1.w = f2bf((v1.w - m) * rstd * g1.w + b1.w);
    *reinterpret_cast<ushort4*>(&s_sn[r * 520 + lane * 4]) = o0;
    *reinterpret_cast<ushort4*>(&s_sn[r * 520 + 256 + lane * 4]) = o1;
    if (ct == 0) {
      ushort4 c0, c1;
      c0.x = f2bf(v0.x); c0.y = f2bf(v0.y); c0.z = f2bf(v0.z); c0.w = f2bf(v0.w);
      c1.x = f2bf(v1.x); c1.y = f2bf(v1.y); c1.z = f2bf(v1.z); c1.w = f2bf(v1.w);
      unsigned short* a2r = A2 + (size_t)(b_ * 16 + r) * 1024 + 512;
      *reinterpret_cast<ushort4*>(a2r + lane * 4) = c0;
      *reinterpret_cast<ushort4*>(a2r + 256 + lane * 4) = c1;
    }
  }

  const unsigned short* Bb = wpt + (size_t)(ct << 7) * 512;
  auto stage = [&](int buf, int k0) {
    #pragma unroll
    for (int i = 0; i < 2; ++i) {
      int ii = w * 2 + i;
      GLD16(Bb + (size_t)((ii << 4) + srow) * 512 + k0 + scol, &sB[buf][ii * 512]);
    }
  };

  f32x4 acc[2];
  acc[0] = f32x4{0.f, 0.f, 0.f, 0.f};
  acc[1] = f32x4{0.f, 0.f, 0.f, 0.f};

  stage(0, 0);
  int cur = 0;
  for (int t = 0; t < 16; ++t) {
    __syncthreads();
    if (t + 1 < 16) stage(cur ^ 1, (t + 1) << 5);
    bf16x8 af = *reinterpret_cast<const bf16x8*>(&s_sn[lrow * 520 + (t << 5) + kt]);
    #pragma unroll
    for (int ni = 0; ni < 2; ++ni) {
      bf16x8 bfv = *reinterpret_cast<const bf16x8*>(&sB[cur][((w * 2 + ni) * 16 + lrow) * 32 + kt]);
      acc[ni] = __builtin_amdgcn_mfma_f32_16x16x32_bf16(af, bfv, acc[ni], 0, 0, 0);
    }
    cur ^= 1;
  }

  const int rb = (lane >> 4) << 2;
  #pragma unroll
  for (int ni = 0; ni < 2; ++ni) {
    int col = (ct << 7) + (w * 2 + ni) * 16 + lrow;
    #pragma unroll
    for (int r = 0; r < 4; ++r) {
      int s = rb + r;
      q2[(size_t)((b_ << 4) + s) * 512 + col] = f2bf(acc[ni][r]);
    }
  }
}

// ---------------- logits[b][16][1024] = q2_b @ x_b^T  (bf16 out) ----------------

__global__ __launch_bounds__(256) void logits_k(
    const unsigned short* __restrict__ q2, const unsigned short* __restrict__ x,
    unsigned short* __restrict__ out) {
  __shared__ unsigned short sA[2][512];   // [16][32]
  __shared__ unsigned short sB[2][4096];  // [128][32]
  const int b = blockIdx.y, nt = blockIdx.x;
  const int lane = threadIdx.x & 63, w = threadIdx.x >> 6;
  const int lrow = lane & 15, kt = (lane >> 4) << 3;
  const int srow = lane >> 2, scol = (lane & 3) << 3;
  const unsigned short* Ab = q2 + ((size_t)b << 13);
  const unsigned short* Bb = x + (((size_t)(b << 10) + (nt << 7)) << 9);

  f32x4 acc[2];
  acc[0] = f32x4{0.f, 0.f, 0.f, 0.f};
  acc[1] = f32x4{0.f, 0.f, 0.f, 0.f};

  auto stage = [&](int buf, int k0) {
    #pragma unroll
    for (int i = 0; i < 2; ++i) {
      int ii = w * 2 + i;
      GLD16(Bb + (size_t)((ii << 4) + srow) * 512 + k0 + scol, &sB[buf][ii * 512]);
    }
    if (w == 0)
      GLD16(Ab + (size_t)srow * 512 + k0 + scol, &sA[buf][0]);
  };

  stage(0, 0);
  int cur = 0;
  for (int t = 0; t < 16; ++t) {
    __syncthreads();
    if (t + 1 < 16) stage(cur ^ 1, (t + 1) << 5);
    bf16x8 af = *reinterpret_cast<const bf16x8*>(&sA[cur][lrow * 32 + kt]);
    #pragma unroll
    for (int ni = 0; ni < 2; ++ni) {
      bf16x8 bfv = *reinterpret_cast<const bf16x8*>(&sB[cur][((w * 2 + ni) * 16 + lrow) * 32 + kt]);
      acc[ni] = __builtin_amdgcn_mfma_f32_16x16x32_bf16(af, bfv, acc[ni], 0, 0, 0);
    }
    cur ^= 1;
  }

  const int rb = (lane >> 4) << 2;
  #pragma unroll
  for (int ni = 0; ni < 2; ++ni) {
    int n = (nt << 7) + (w * 2 + ni) * 16 + lrow;
    #pragma unroll
    for (int r = 0; r < 4; ++r) {
      int s = rb + r;
      out[(size_t)((b << 4) + s) * 1024 + n] = f2bf(acc[ni][r]);
    }
  }
}

// ---------------- pv_sm: softmax+colnorm (LDS attn) + PV MFMA ----------------
// grid (4 d-tiles, 64 b), block 256. logits bf16.

__global__ __launch_bounds__(256) void pv_sm_k(
    const unsigned short* __restrict__ logits, const unsigned short* __restrict__ vT,
    unsigned short* __restrict__ A2) {
  __shared__ float s_mi[16][2];
  __shared__ unsigned short s_at[16 * 1032];  // [16][1032]
  __shared__ unsigned short sA[2][4096];      // [128 d][32 n]
  const int b_ = blockIdx.y, dt = blockIdx.x;
  const int lane = threadIdx.x & 63, w = threadIdx.x >> 6;
  const int lrow = lane & 15, kt = (lane >> 4) << 3;
  const int srow = lane >> 2, scol = (lane & 3) << 3;
  const unsigned short* lg = logits + ((size_t)b_ << 14);

  // phase 1: row softmax stats (wave w -> rows 4w..4w+3)
  #pragma unroll
  for (int rr = 0; rr < 4; ++rr) {
    int r = w * 4 + rr;
    const unsigned short* rp = lg + (size_t)r * 1024;
    float v[16];
    float mx = -3.4e38f;
    #pragma unroll
    for (int i = 0; i < 16; ++i) { v[i] = bf2f(rp[lane + (i << 6)]); mx = fmaxf(mx, v[i]); }
    #pragma unroll
    for (int o = 32; o > 0; o >>= 1) mx = fmaxf(mx, __shfl_xor(mx, o));
    float s = 0.f;
    #pragma unroll
    for (int i = 0; i < 16; ++i) s += __expf(v[i] - mx);
    #pragma unroll
    for (int o = 32; o > 0; o >>= 1) s += __shfl_xor(s, o);
    if (lane == 0) { s_mi[r][0] = mx; s_mi[r][1] = 1.0f / s; }
  }
  __syncthreads();

  // phase 2: column sums + normalized attn -> LDS bf16
  #pragma unroll
  for (int j = 0; j < 4; ++j) {
    int c = threadIdx.x + (j << 8);
    float e[16];
    float cs = 0.f;
    #pragma unroll
    for (int s = 0; s < 16; ++s) {
      e[s] = __expf(bf2f(lg[(size_t)s * 1024 + c]) - s_mi[s][0]) * s_mi[s][1];
      cs += e[s];
    }
    float rv = 1.0f / (cs + 1e-8f);
    #pragma unroll
    for (int s = 0; s < 16; ++s) s_at[s * 1032 + c] = f2bf(e[s] * rv);
  }

  // phase 3: PV MFMA (A = vT stripe staged, B = attn from LDS)
  const unsigned short* Ab = vT + ((size_t)b_ << 19) + (size_t)(dt << 7) * 1024;
  auto stage = [&](int buf, int k0) {
    #pragma unroll
    for (int i = 0; i < 2; ++i) {
      int ii = w * 2 + i;
      GLD16(Ab + (size_t)((ii << 4) + srow) * 1024 + k0 + scol, &sA[buf][ii * 512]);
    }
  };

  f32x4 acc[2];
  acc[0] = f32x4{0.f, 0.f, 0.f, 0.f};
  acc[1] = f32x4{0.f, 0.f, 0.f, 0.f};

  stage(0, 0);
  int cur = 0;
  for (int t = 0; t < 32; ++t) {
    __syncthreads();
    if (t + 1 < 32) stage(cur ^ 1, (t + 1) << 5);
    bf16x8 bfv = *reinterpret_cast<const bf16x8*>(&s_at[lrow * 1032 + (t << 5) + kt]);
    #pragma unroll
    for (int mi = 0; mi < 2; ++mi) {
      bf16x8 af = *reinterpret_cast<const bf16x8*>(&sA[cur][((w * 2 + mi) * 16 + lrow) * 32 + kt]);
      acc[mi] = __builtin_amdgcn_mfma_f32_16x16x32_bf16(af, bfv, acc[mi], 0, 0, 0);
    }
    cur ^= 1;
  }

  const int rb = (lane >> 4) << 2;
  const int s = lrow;
  #pragma unroll
  for (int mi = 0; mi < 2; ++mi) {
    int d0 = (dt << 7) + (w * 2 + mi) * 16 + rb;
    ushort4 o;
    o.x = f2bf(acc[mi][0]); o.y = f2bf(acc[mi][1]);
    o.z = f2bf(acc[mi][2]); o.w = f2bf(acc[mi][3]);
    *reinterpret_cast<ushort4*>(&A2[(size_t)((b_ << 4) + s) * 1024 + d0]) = o;
  }
}

// ---------------- MFMA GEMM 64x64 (weight prep only) ----------------

template<int OUTBF16, int SCALE>
__global__ __launch_bounds__(256) void gemm_sm(
    const unsigned short* __restrict__ A, const unsigned short* __restrict__ W,
    void* __restrict__ Cout, int M, int N, int K, float scalev) {
  __shared__ unsigned short sA[2][2048];
  __shared__ unsigned short sB[2][2048];
  const int tid = threadIdx.x;
  const int lane = tid & 63, w = tid >> 6;

  int nwg = gridDim.x * gridDim.y;
  int flat = blockIdx.y * gridDim.x + blockIdx.x;
  if ((nwg & 7) == 0) { int c = nwg >> 3; flat = (flat & 7) * c + (flat >> 3); }
  const int row0 = (flat / gridDim.x) << 6;
  const int col0 = (flat % gridDim.x) << 6;

  const int lrow = lane & 15, kt = (lane >> 4) << 3;
  const int srow = lane >> 2, scol = (lane & 3) << 3;

  f32x4 acc[4];
  #pragma unroll
  for (int m = 0; m < 4; ++m) acc[m] = f32x4{0.f, 0.f, 0.f, 0.f};

  auto stage = [&](int buf, int k0) {
    int r = (w << 4) + srow;
    GLD16(A + (size_t)(row0 + r) * K + k0 + scol, &sA[buf][w * 512]);
    GLD16(W + (size_t)(col0 + r) * K + k0 + scol, &sB[buf][w * 512]);
  };

  stage(0, 0);
  const int nt = K >> 5;
  int cur = 0;
  for (int t = 0; t < nt; ++t) {
    __syncthreads();
    if (t + 1 < nt) stage(cur ^ 1, (t + 1) << 5);
    bf16x8 af[4], bfv;
    #pragma unroll
    for (int m = 0; m < 4; ++m)
      af[m] = *reinterpret_cast<const bf16x8*>(&sA[cur][(m * 16 + lrow) * 32 + kt]);
    bfv = *reinterpret_cast<const bf16x8*>(&sB[cur][((w << 4) + lrow) * 32 + kt]);
    #pragma unroll
    for (int m = 0; m < 4; ++m)
      acc[m] = __builtin_amdgcn_mfma_f32_16x16x32_bf16(af[m], bfv, acc[m], 0, 0, 0);
    cur ^= 1;
  }

  const int rb = (lane >> 4) << 2;
  const int col = col0 + (w << 4) + lrow;
  #pragma unroll
  for (int m = 0; m < 4; ++m) {
    #pragma unroll
    for (int r = 0; r < 4; ++r) {
      int row = row0 + m * 16 + rb + r;
      float v = acc[m][r];
      if (SCALE) v *= scalev;
      if (OUTBF16) ((unsigned short*)Cout)[(size_t)row * N + col] = f2bf(v);
      else ((float*)Cout)[(size_t)row * N + col] = v;
    }
  }
}

// ---------------- host launch ----------------

extern "C" void kernel_launch(void* const* d_in, const int* in_sizes, int n_in,
                              void* d_out, int out_size, void* d_ws, size_t ws_size,
                              hipStream_t stream) {
  const float* inputs  = (const float*)d_in[0];
  const float* noise   = (const float*)d_in[1];
  const float* slot_mu = (const float*)d_in[2];
  const float* slot_ls = (const float*)d_in[3];
  const float* ln_in_g = (const float*)d_in[4];
  const float* ln_in_b = (const float*)d_in[5];
  const float* ln_s_g  = (const float*)d_in[6];
  const float* ln_s_b  = (const float*)d_in[7];
  const float* ln_m_g  = (const float*)d_in[8];
  const float* ln_m_b  = (const float*)d_in[9];
  const float* Wq   = (const float*)d_in[10];
  const float* Wk   = (const float*)d_in[11];
  const float* Wv   = (const float*)d_in[12];
  const float* w_ih = (const float*)d_in[13];
  const float* w_hh = (const float*)d_in[14];
  const float* b_ih = (const float*)d_in[15];
  const float* b_hh = (const float*)d_in[16];
  const float* w1   = (const float*)d_in[17];
  const float* b1   = (const float*)d_in[18];
  const float* w2   = (const float*)d_in[19];
  const float* b2   = (const float*)d_in[20];

  const int BN = 65536, BS = 1024;

  uintptr_t base = (uintptr_t)d_ws;
  auto alloc = [&](size_t bytes) {
    void* p = (void*)base;
    base += (bytes + 255) & ~(size_t)255;
    return p;
  };
  unsigned short* x_bf    = (unsigned short*)alloc((size_t)BN * 512 * 2);
  unsigned short* vT      = (unsigned short*)alloc((size_t)64 * 512 * 1024 * 2);
  unsigned short* wqT     = (unsigned short*)alloc(512 * 512 * 2);
  unsigned short* wkT     = (unsigned short*)alloc(512 * 512 * 2);
  unsigned short* wpt     = (unsigned short*)alloc(512 * 512 * 2);
  unsigned short* wv_bf   = (unsigned short*)alloc(512 * 512 * 2);
  unsigned short* wcat_bf = (unsigned short*)alloc((size_t)2048 * 1024 * 2);
  float*          bcat    = (float*)alloc(2048 * 4);
  unsigned short* w1_bf   = (unsigned short*)alloc(512 * 512 * 2);
  unsigned short* w2_bf   = (unsigned short*)alloc(512 * 512 * 2);
  float*          slots   = (float*)alloc((size_t)BS * 512 * 4);
  unsigned short* A2      = (unsigned short*)alloc((size_t)BS * 1024 * 2);
  unsigned short* q2_bf   = (unsigned short*)alloc((size_t)BS * 512 * 2);
  unsigned short* logits  = (unsigned short*)alloc((size_t)64 * 16 * 1024 * 2);
  float*          gates   = (float*)alloc((size_t)BS * 2048 * 4);
  float*          sgru    = (float*)alloc((size_t)BS * 512 * 4);
  unsigned short* lnm_bf  = (unsigned short*)alloc((size_t)BS * 512 * 2);
  unsigned short* h_bf    = (unsigned short*)alloc((size_t)BS * 512 * 2);
  (void)ws_size; (void)n_in; (void)in_sizes; (void)out_size;

  const float scale = 0.044194173824159216f;  // 512^-0.5

  // prologue (5 dispatches)
  wprep_k<<<13320, 256, 0, stream>>>(Wv, w1, w2, w_ih, w_hh, b_ih, b_hh,
                                     slot_mu, slot_ls, noise,
                                     wv_bf, w1_bf, w2_bf, wcat_bf, bcat, slots);
  tcast2_k<<<dim3(16, 16, 2), 256, 0, stream>>>(Wq, Wk, wqT, wkT);
  gemm_sm<1,1><<<dim3(8, 8), 256, 0, stream>>>(
      wkT, wqT, wpt, 512, 512, 512, scale);
  ln_rows_k<<<16384, 256, 0, stream>>>(inputs, ln_in_g, ln_in_b, x_bf, BN);
  gemm_vt<<<dim3(4, 512), 256, 0, stream>>>(x_bf, wv_bf, vT);

  for (int it = 0; it < 3; ++it) {
    q2ln_k<<<dim3(4, 64), 256, 0, stream>>>(slots, ln_s_g, ln_s_b, wpt, q2_bf, A2);
    logits_k<<<dim3(8, 64), 256, 0, stream>>>(q2_bf, x_bf, logits);
    pv_sm_k<<<dim3(4, 64), 256, 0, stream>>>(logits, vT, A2);
    gemm_bt<1,0,0,0><<<dim3(16, 8), 256, 0, stream>>>(
        A2, wcat_bf, bcat, nullptr, gates, BS, 2048, 1024);
    gru_ln_k<<<256, 256, 0, stream>>>(gates, slots, ln_m_g, ln_m_b, sgru, lnm_bf);
    gemm_bt<1,1,0,1><<<dim3(4, 8), 256, 0, stream>>>(
        lnm_bf, w1_bf, b1, nullptr, h_bf, BS, 512, 512);
    float* slots_out = (it == 2) ? (float*)d_out : slots;
    gemm_bt<1,0,1,0><<<dim3(4, 8), 256, 0, stream>>>(
        h_bf, w2_bf, b2, sgru, slots_out, BS, 512, 512);
  }
}

// Round 9
// 343.961 us; speedup vs baseline: 1.1802x; 1.1802x over previous
//
#include <hip/hip_runtime.h>
#include <hip/hip_bf16.h>
#include <cstdint>
#include <cstddef>

// Shapes fixed: B=64, N=1024, D=512, S=16, 3 iterations.
// Algebra: logits = sn·W'·x^T, W' = scale·Wq^T·Wk   (k never materialized)
//          ax = attn·x;  upd@Wih^T = ax@(Wih·Wv)^T  (v never materialized)

typedef __bf16 bf16x8 __attribute__((ext_vector_type(8)));
typedef float f32x4 __attribute__((ext_vector_type(4)));

__device__ __forceinline__ float bf2f(unsigned int u) {
  union { unsigned int i; float f; } v; v.i = u << 16; return v.f;
}
__device__ __forceinline__ unsigned short f2bf(float x) {
  __hip_bfloat16 h = __float2bfloat16(x);
  unsigned short u;
  __builtin_memcpy(&u, &h, 2);
  return u;
}

#define GLD16(gp, lp)                                                       \
  __builtin_amdgcn_global_load_lds(                                         \
      (const __attribute__((address_space(1))) void*)(gp),                  \
      (__attribute__((address_space(3))) void*)(lp), 16, 0, 0)

// ---------------- merged prep (segmented): w1,w2,wih casts, bcat, slots ----------------

__global__ void wprep_k(const float* __restrict__ w1, const float* __restrict__ w2,
                        const float* __restrict__ wih, const float* __restrict__ bih,
                        const float* __restrict__ bhh, const float* __restrict__ mu,
                        const float* __restrict__ ls, const float* __restrict__ noise,
                        unsigned short* __restrict__ w1_bf, unsigned short* __restrict__ w2_bf,
                        unsigned short* __restrict__ wih_bf, float* __restrict__ bcat,
                        float* __restrict__ slots) {
  int blk = blockIdx.x, t = threadIdx.x;
  if (blk < 1024) {
    int i = blk * 256 + t; w1_bf[i] = f2bf(w1[i]);
  } else if (blk < 2048) {
    int i = (blk - 1024) * 256 + t; w2_bf[i] = f2bf(w2[i]);
  } else if (blk < 5120) {
    int i = (blk - 2048) * 256 + t; wih_bf[i] = f2bf(wih[i]);
  } else if (blk < 5128) {
    int j = (blk - 5120) * 256 + t;  // 2048
    float v;
    if (j < 1024)      v = bih[j] + bhh[j];
    else if (j < 1536) v = bih[j];
    else               v = bhh[j - 512];
    bcat[j] = v;
  } else {
    int i = (blk - 5128) * 256 + t;  // 524288
    int d = i & 511;
    slots[i] = mu[d] + expf(ls[d]) * noise[i];
  }
}

// Wcat [2048][1024] from wihp (f32) and whh (f32):
// j<1024: [wihp[j] | whh[j]]; [1024,1536): [wihp[j] | 0]; [1536,2048): [0 | whh[j-512]]
__global__ void wcat_k(const float* __restrict__ wihp, const float* __restrict__ whh,
                       unsigned short* __restrict__ out) {
  int i = blockIdx.x * 256 + threadIdx.x;  // 2M total
  int j = i >> 10, k = i & 1023;
  float v;
  if (j < 1024)      v = (k < 512) ? wihp[j * 512 + k] : whh[j * 512 + (k - 512)];
  else if (j < 1536) v = (k < 512) ? wihp[j * 512 + k] : 0.0f;
  else               v = (k < 512) ? 0.0f : whh[(j - 512) * 512 + (k - 512)];
  out[i] = f2bf(v);
}

// transpose + cast Wq, Wk, Wv: grid (16,16,3)
__global__ __launch_bounds__(256) void tcast3_k(const float* __restrict__ Wq,
                                                const float* __restrict__ Wk,
                                                const float* __restrict__ Wv,
                                                unsigned short* __restrict__ wqT,
                                                unsigned short* __restrict__ wkT,
                                                unsigned short* __restrict__ wvT) {
  __shared__ float tt[32][33];
  const float* in = blockIdx.z == 0 ? Wq : (blockIdx.z == 1 ? Wk : Wv);
  unsigned short* out = blockIdx.z == 0 ? wqT : (blockIdx.z == 1 ? wkT : wvT);
  int c0 = blockIdx.x << 5, r0 = blockIdx.y << 5;
  int tx = threadIdx.x & 31, ty = threadIdx.x >> 5;
  #pragma unroll
  for (int i = 0; i < 4; ++i)
    tt[ty + 8 * i][tx] = in[(size_t)(r0 + ty + 8 * i) * 512 + c0 + tx];
  __syncthreads();
  #pragma unroll
  for (int i = 0; i < 4; ++i)
    out[(size_t)(c0 + ty + 8 * i) * 512 + r0 + tx] = f2bf(tt[tx][ty + 8 * i]);
}

// ---------------- layernorm inputs (wave per row, D=512) ----------------

__global__ __launch_bounds__(256) void ln_rows_k(
    const float* __restrict__ in, const float* __restrict__ g, const float* __restrict__ b,
    unsigned short* __restrict__ out, int rows) {
  int w = threadIdx.x >> 6, lane = threadIdx.x & 63;
  int row = (blockIdx.x << 2) + w;
  if (row >= rows) return;
  const float4* rp = reinterpret_cast<const float4*>(in + (size_t)row * 512);
  float4 v0 = rp[lane], v1 = rp[lane + 64];
  float s = v0.x + v0.y + v0.z + v0.w + v1.x + v1.y + v1.z + v1.w;
  float q = v0.x*v0.x + v0.y*v0.y + v0.z*v0.z + v0.w*v0.w
          + v1.x*v1.x + v1.y*v1.y + v1.z*v1.z + v1.w*v1.w;
  #pragma unroll
  for (int o = 32; o > 0; o >>= 1) { s += __shfl_xor(s, o); q += __shfl_xor(q, o); }
  float m = s * (1.0f / 512.0f);
  float rstd = rsqrtf(q * (1.0f / 512.0f) - m * m + 1e-8f);
  const float4* gp = reinterpret_cast<const float4*>(g);
  const float4* bp = reinterpret_cast<const float4*>(b);
  float4 g0 = gp[lane], g1 = gp[lane + 64];
  float4 b0 = bp[lane], b1 = bp[lane + 64];
  ushort4 o0, o1;
  o0.x = f2bf((v0.x - m) * rstd * g0.x + b0.x);
  o0.y = f2bf((v0.y - m) * rstd * g0.y + b0.y);
  o0.z = f2bf((v0.z - m) * rstd * g0.z + b0.z);
  o0.w = f2bf((v0.w - m) * rstd * g0.w + b0.w);
  o1.x = f2bf((v1.x - m) * rstd * g1.x + b1.x);
  o1.y = f2bf((v1.y - m) * rstd * g1.y + b1.y);
  o1.z = f2bf((v1.z - m) * rstd * g1.z + b1.z);
  o1.w = f2bf((v1.w - m) * rstd * g1.w + b1.w);
  ushort4* op = reinterpret_cast<ushort4*>(out + (size_t)row * 512);
  op[lane] = o0; op[lane + 64] = o1;
}

// ---------------- xT[b][e][n] = x_bf[b*1024+n][e]  (64x64 LDS tiles) ----------------
// grid (16 nt, 8 et, 64 b), block 256

__global__ __launch_bounds__(256) void xt_k(const unsigned short* __restrict__ x,
                                            unsigned short* __restrict__ xT) {
  __shared__ unsigned short t[64][68];
  int nt = blockIdx.x, et = blockIdx.y, b = blockIdx.z;
  int r = threadIdx.x >> 3, c8 = (threadIdx.x & 7) << 3;
  #pragma unroll
  for (int p = 0; p < 2; ++p) {
    int row = r + (p << 5);
    *reinterpret_cast<uint4*>(&t[row][c8]) = *reinterpret_cast<const uint4*>(
        x + ((size_t)(b << 10) + (nt << 6) + row) * 512 + (et << 6) + c8);
  }
  __syncthreads();
  #pragma unroll
  for (int p = 0; p < 2; ++p) {
    int erow = r + (p << 5);
    ushort4 a, bb;
    #pragma unroll
    for (int j = 0; j < 4; ++j) ((unsigned short*)&a)[j] = t[c8 + j][erow];
    #pragma unroll
    for (int j = 0; j < 4; ++j) ((unsigned short*)&bb)[j] = t[c8 + 4 + j][erow];
    unsigned short* o = xT + ((size_t)(b << 9) + (et << 6) + erow) * 1024 + (nt << 6) + c8;
    *reinterpret_cast<ushort4*>(o) = a;
    *reinterpret_cast<ushort4*>(o + 4) = bb;
  }
}

// GRU (fused-gates layout) + LN: gates[row][2048] = [rsum, zsum, i_n, h_n]
__global__ __launch_bounds__(256) void gru_ln_k(
    const float* __restrict__ gates, const float* __restrict__ hp,
    const float* __restrict__ g, const float* __restrict__ b,
    float* __restrict__ sgru, unsigned short* __restrict__ lnm) {
  int w = threadIdx.x >> 6, lane = threadIdx.x & 63;
  int row = (blockIdx.x << 2) + w;
  size_t gb = (size_t)row * 2048 + (lane << 3);
  size_t hb = (size_t)row * 512 + (lane << 3);
  float rs[8], zs[8], in_[8], hn[8], hv[8], y[8];
  #pragma unroll
  for (int c = 0; c < 2; ++c) {
    *reinterpret_cast<float4*>(rs + 4*c)  = *reinterpret_cast<const float4*>(gates + gb + 4*c);
    *reinterpret_cast<float4*>(zs + 4*c)  = *reinterpret_cast<const float4*>(gates + gb + 512 + 4*c);
    *reinterpret_cast<float4*>(in_ + 4*c) = *reinterpret_cast<const float4*>(gates + gb + 1024 + 4*c);
    *reinterpret_cast<float4*>(hn + 4*c)  = *reinterpret_cast<const float4*>(gates + gb + 1536 + 4*c);
    *reinterpret_cast<float4*>(hv + 4*c)  = *reinterpret_cast<const float4*>(hp + hb + 4*c);
  }
  float s = 0.f, q = 0.f;
  #pragma unroll
  for (int j = 0; j < 8; ++j) {
    float r = 1.0f / (1.0f + expf(-rs[j]));
    float z = 1.0f / (1.0f + expf(-zs[j]));
    float n = tanhf(in_[j] + r * hn[j]);
    float h = (1.0f - z) * n + z * hv[j];
    y[j] = h; s += h; q += h * h;
  }
  #pragma unroll
  for (int o = 32; o > 0; o >>= 1) { s += __shfl_xor(s, o); q += __shfl_xor(q, o); }
  float m = s * (1.0f / 512.0f);
  float rstd = rsqrtf(q * (1.0f / 512.0f) - m * m + 1e-8f);
  const float* gg = g + (lane << 3);
  const float* bb = b + (lane << 3);
  #pragma unroll
  for (int c = 0; c < 2; ++c)
    *reinterpret_cast<float4*>(sgru + hb + 4*c) = *reinterpret_cast<const float4*>(y + 4*c);
  uint4 o4;
  unsigned int p[8];
  #pragma unroll
  for (int j = 0; j < 8; ++j) p[j] = f2bf((y[j] - m) * rstd * gg[j] + bb[j]);
  o4.x = p[0] | (p[1] << 16); o4.y = p[2] | (p[3] << 16);
  o4.z = p[4] | (p[5] << 16); o4.w = p[6] | (p[7] << 16);
  *reinterpret_cast<uint4*>(lnm + hb) = o4;
}

// ---------------- MFMA GEMM 128x128 (prologue wih' only) ----------------

template<int OUTBF16>
__global__ __launch_bounds__(256) void gemm_bt(
    const unsigned short* __restrict__ A, const unsigned short* __restrict__ W,
    void* __restrict__ Cout, int M, int N, int K) {
  __shared__ unsigned short sA[2][4096];
  __shared__ unsigned short sB[2][4096];
  const int tid = threadIdx.x;
  const int lane = tid & 63, w = tid >> 6;

  int nwg = gridDim.x * gridDim.y;
  int flat = blockIdx.y * gridDim.x + blockIdx.x;
  if ((nwg & 7) == 0) { int c = nwg >> 3; flat = (flat & 7) * c + (flat >> 3); }
  const int row0 = (flat / gridDim.x) << 7;
  const int col0 = (flat % gridDim.x) << 7;

  const int wm = (w >> 1) << 6, wn = (w & 1) << 6;
  const int lrow = lane & 15, kt = (lane >> 4) << 3;
  const int srow = lane >> 2, scol = (lane & 3) << 3;

  f32x4 acc[4][4];
  #pragma unroll
  for (int m = 0; m < 4; ++m)
    #pragma unroll
    for (int n = 0; n < 4; ++n) acc[m][n] = f32x4{0.f, 0.f, 0.f, 0.f};

  auto stage = [&](int buf, int k0) {
    #pragma unroll
    for (int i = 0; i < 2; ++i) {
      int ii = w * 2 + i;
      int r = (ii << 4) + srow;
      GLD16(A + (size_t)(row0 + r) * K + k0 + scol, &sA[buf][ii * 512]);
      GLD16(W + (size_t)(col0 + r) * K + k0 + scol, &sB[buf][ii * 512]);
    }
  };

  stage(0, 0);
  const int nt = K >> 5;
  int cur = 0;
  for (int t = 0; t < nt; ++t) {
    __syncthreads();
    if (t + 1 < nt) stage(cur ^ 1, (t + 1) << 5);
    bf16x8 af[4], bfv[4];
    #pragma unroll
    for (int m = 0; m < 4; ++m)
      af[m] = *reinterpret_cast<const bf16x8*>(&sA[cur][(wm + m * 16 + lrow) * 32 + kt]);
    #pragma unroll
    for (int n = 0; n < 4; ++n)
      bfv[n] = *reinterpret_cast<const bf16x8*>(&sB[cur][(wn + n * 16 + lrow) * 32 + kt]);
    #pragma unroll
    for (int m = 0; m < 4; ++m)
      #pragma unroll
      for (int n = 0; n < 4; ++n)
        acc[m][n] = __builtin_amdgcn_mfma_f32_16x16x32_bf16(af[m], bfv[n], acc[m][n], 0, 0, 0);
    cur ^= 1;
  }

  const int rb = (lane >> 4) << 2;
  #pragma unroll
  for (int m = 0; m < 4; ++m) {
    #pragma unroll
    for (int n = 0; n < 4; ++n) {
      int col = col0 + wn + n * 16 + lrow;
      #pragma unroll
      for (int r = 0; r < 4; ++r) {
        int row = row0 + wm + m * 16 + rb + r;
        float v = acc[m][n][r];
        if (OUTBF16) ((unsigned short*)Cout)[(size_t)row * N + col] = f2bf(v);
        else ((float*)Cout)[(size_t)row * N + col] = v;
      }
    }
  }
}

// ---------------- q2ln: LN(slots_b) in LDS, then q2 = sn @ W' tile ----------------

__global__ __launch_bounds__(256) void q2ln_k(
    const float* __restrict__ slots, const float* __restrict__ g, const float* __restrict__ b,
    const unsigned short* __restrict__ wpt, unsigned short* __restrict__ q2,
    unsigned short* __restrict__ A2) {
  __shared__ unsigned short s_sn[16 * 520];
  __shared__ unsigned short sB[2][4096];
  const int b_ = blockIdx.y, ct = blockIdx.x;
  const int lane = threadIdx.x & 63, w = threadIdx.x >> 6;
  const int lrow = lane & 15, kt = (lane >> 4) << 3;
  const int srow = lane >> 2, scol = (lane & 3) << 3;

  const float4* gp = reinterpret_cast<const float4*>(g);
  const float4* bp = reinterpret_cast<const float4*>(b);
  float4 g0 = gp[lane], g1 = gp[lane + 64];
  float4 b0 = bp[lane], b1 = bp[lane + 64];
  #pragma unroll
  for (int rr = 0; rr < 4; ++rr) {
    int r = w * 4 + rr;
    const float4* rp = reinterpret_cast<const float4*>(slots + (size_t)(b_ * 16 + r) * 512);
    float4 v0 = rp[lane], v1 = rp[lane + 64];
    float s = v0.x + v0.y + v0.z + v0.w + v1.x + v1.y + v1.z + v1.w;
    float q = v0.x*v0.x + v0.y*v0.y + v0.z*v0.z + v0.w*v0.w
            + v1.x*v1.x + v1.y*v1.y + v1.z*v1.z + v1.w*v1.w;
    #pragma unroll
    for (int o = 32; o > 0; o >>= 1) { s += __shfl_xor(s, o); q += __shfl_xor(q, o); }
    float m = s * (1.0f / 512.0f);
    float rstd = rsqrtf(q * (1.0f / 512.0f) - m * m + 1e-8f);
    ushort4 o0, o1;
    o0.x = f2bf((v0.x - m) * rstd * g0.x + b0.x);
    o0.y = f2bf((v0.y - m) * rstd * g0.y + b0.y);
    o0.z = f2bf((v0.z - m) * rstd * g0.z + b0.z);
    o0.w = f2bf((v0.w - m) * rstd * g0.w + b0.w);
    o1.x = f2bf((v1.x - m) * rstd * g1.x + b1.x);
    o1.y = f2bf((v1.y - m) * rstd * g1.y + b1.y);
    o1.z = f2bf((v1.z - m) * rstd * g1.z + b1.z);
    o1.w = f2bf((v1.w - m) * rstd * g1.w + b1.w);
    *reinterpret_cast<ushort4*>(&s_sn[r * 520 + lane * 4]) = o0;
    *reinterpret_cast<ushort4*>(&s_sn[r * 520 + 256 + lane * 4]) = o1;
    if (ct == 0) {
      ushort4 c0, c1;
      c0.x = f2bf(v0.x); c0.y = f2bf(v0.y); c0.z = f2bf(v0.z); c0.w = f2bf(v0.w);
      c1.x = f2bf(v1.x); c1.y = f2bf(v1.y); c1.z = f2bf(v1.z); c1.w = f2bf(v1.w);
      unsigned short* a2r = A2 + (size_t)(b_ * 16 + r) * 1024 + 512;
      *reinterpret_cast<ushort4*>(a2r + lane * 4) = c0;
      *reinterpret_cast<ushort4*>(a2r + 256 + lane * 4) = c1;
    }
  }

  const unsigned short* Bb = wpt + (size_t)(ct << 7) * 512;
  auto stage = [&](int buf, int k0) {
    #pragma unroll
    for (int i = 0; i < 2; ++i) {
      int ii = w * 2 + i;
      GLD16(Bb + (size_t)((ii << 4) + srow) * 512 + k0 + scol, &sB[buf][ii * 512]);
    }
  };

  f32x4 acc[2];
  acc[0] = f32x4{0.f, 0.f, 0.f, 0.f};
  acc[1] = f32x4{0.f, 0.f, 0.f, 0.f};

  stage(0, 0);
  int cur = 0;
  for (int t = 0; t < 16; ++t) {
    __syncthreads();
    if (t + 1 < 16) stage(cur ^ 1, (t + 1) << 5);
    bf16x8 af = *reinterpret_cast<const bf16x8*>(&s_sn[lrow * 520 + (t << 5) + kt]);
    #pragma unroll
    for (int ni = 0; ni < 2; ++ni) {
      bf16x8 bfv = *reinterpret_cast<const bf16x8*>(&sB[cur][((w * 2 + ni) * 16 + lrow) * 32 + kt]);
      acc[ni] = __builtin_amdgcn_mfma_f32_16x16x32_bf16(af, bfv, acc[ni], 0, 0, 0);
    }
    cur ^= 1;
  }

  const int rb = (lane >> 4) << 2;
  #pragma unroll
  for (int ni = 0; ni < 2; ++ni) {
    int col = (ct << 7) + (w * 2 + ni) * 16 + lrow;
    #pragma unroll
    for (int r = 0; r < 4; ++r) {
      int s = rb + r;
      q2[(size_t)((b_ << 4) + s) * 512 + col] = f2bf(acc[ni][r]);
    }
  }
}

// ---------------- logits[b][16][1024] = q2_b @ x_b^T  (bf16 out) ----------------

__global__ __launch_bounds__(256) void logits_k(
    const unsigned short* __restrict__ q2, const unsigned short* __restrict__ x,
    unsigned short* __restrict__ out) {
  __shared__ unsigned short sA[2][512];
  __shared__ unsigned short sB[2][4096];
  const int b = blockIdx.y, nt = blockIdx.x;
  const int lane = threadIdx.x & 63, w = threadIdx.x >> 6;
  const int lrow = lane & 15, kt = (lane >> 4) << 3;
  const int srow = lane >> 2, scol = (lane & 3) << 3;
  const unsigned short* Ab = q2 + ((size_t)b << 13);
  const unsigned short* Bb = x + (((size_t)(b << 10) + (nt << 7)) << 9);

  f32x4 acc[2];
  acc[0] = f32x4{0.f, 0.f, 0.f, 0.f};
  acc[1] = f32x4{0.f, 0.f, 0.f, 0.f};

  auto stage = [&](int buf, int k0) {
    #pragma unroll
    for (int i = 0; i < 2; ++i) {
      int ii = w * 2 + i;
      GLD16(Bb + (size_t)((ii << 4) + srow) * 512 + k0 + scol, &sB[buf][ii * 512]);
    }
    if (w == 0)
      GLD16(Ab + (size_t)srow * 512 + k0 + scol, &sA[buf][0]);
  };

  stage(0, 0);
  int cur = 0;
  for (int t = 0; t < 16; ++t) {
    __syncthreads();
    if (t + 1 < 16) stage(cur ^ 1, (t + 1) << 5);
    bf16x8 af = *reinterpret_cast<const bf16x8*>(&sA[cur][lrow * 32 + kt]);
    #pragma unroll
    for (int ni = 0; ni < 2; ++ni) {
      bf16x8 bfv = *reinterpret_cast<const bf16x8*>(&sB[cur][((w * 2 + ni) * 16 + lrow) * 32 + kt]);
      acc[ni] = __builtin_amdgcn_mfma_f32_16x16x32_bf16(af, bfv, acc[ni], 0, 0, 0);
    }
    cur ^= 1;
  }

  const int rb = (lane >> 4) << 2;
  #pragma unroll
  for (int ni = 0; ni < 2; ++ni) {
    int n = (nt << 7) + (w * 2 + ni) * 16 + lrow;
    #pragma unroll
    for (int r = 0; r < 4; ++r) {
      int s = rb + r;
      out[(size_t)((b << 4) + s) * 1024 + n] = f2bf(acc[ni][r]);
    }
  }
}

// ---------------- pv_sm: softmax+colnorm (LDS attn) + ax MFMA vs xT ----------------
// grid (4 e-tiles, 64 b), block 256. ax[s][e] -> A2 left half.

__global__ __launch_bounds__(256) void pv_sm_k(
    const unsigned short* __restrict__ logits, const unsigned short* __restrict__ xT,
    unsigned short* __restrict__ A2) {
  __shared__ float s_mi[16][2];
  __shared__ unsigned short s_at[16 * 1032];
  __shared__ unsigned short sA[2][4096];  // [128 e][32 n]
  const int b_ = blockIdx.y, et = blockIdx.x;
  const int lane = threadIdx.x & 63, w = threadIdx.x >> 6;
  const int lrow = lane & 15, kt = (lane >> 4) << 3;
  const int srow = lane >> 2, scol = (lane & 3) << 3;
  const unsigned short* lg = logits + ((size_t)b_ << 14);

  // phase 1: row softmax stats
  #pragma unroll
  for (int rr = 0; rr < 4; ++rr) {
    int r = w * 4 + rr;
    const unsigned short* rp = lg + (size_t)r * 1024;
    float v[16];
    float mx = -3.4e38f;
    #pragma unroll
    for (int i = 0; i < 16; ++i) { v[i] = bf2f(rp[lane + (i << 6)]); mx = fmaxf(mx, v[i]); }
    #pragma unroll
    for (int o = 32; o > 0; o >>= 1) mx = fmaxf(mx, __shfl_xor(mx, o));
    float s = 0.f;
    #pragma unroll
    for (int i = 0; i < 16; ++i) s += __expf(v[i] - mx);
    #pragma unroll
    for (int o = 32; o > 0; o >>= 1) s += __shfl_xor(s, o);
    if (lane == 0) { s_mi[r][0] = mx; s_mi[r][1] = 1.0f / s; }
  }
  __syncthreads();

  // phase 2: column norm -> LDS bf16
  #pragma unroll
  for (int j = 0; j < 4; ++j) {
    int c = threadIdx.x + (j << 8);
    float e[16];
    float cs = 0.f;
    #pragma unroll
    for (int s = 0; s < 16; ++s) {
      e[s] = __expf(bf2f(lg[(size_t)s * 1024 + c]) - s_mi[s][0]) * s_mi[s][1];
      cs += e[s];
    }
    float rv = 1.0f / (cs + 1e-8f);
    #pragma unroll
    for (int s = 0; s < 16; ++s) s_at[s * 1032 + c] = f2bf(e[s] * rv);
  }

  // phase 3: ax^T via MFMA (A = xT stripe, B = attn from LDS)
  const unsigned short* Ab = xT + ((size_t)b_ << 19) + (size_t)(et << 7) * 1024;
  auto stage = [&](int buf, int k0) {
    #pragma unroll
    for (int i = 0; i < 2; ++i) {
      int ii = w * 2 + i;
      GLD16(Ab + (size_t)((ii << 4) + srow) * 1024 + k0 + scol, &sA[buf][ii * 512]);
    }
  };

  f32x4 acc[2];
  acc[0] = f32x4{0.f, 0.f, 0.f, 0.f};
  acc[1] = f32x4{0.f, 0.f, 0.f, 0.f};

  stage(0, 0);
  int cur = 0;
  for (int t = 0; t < 32; ++t) {
    __syncthreads();
    if (t + 1 < 32) stage(cur ^ 1, (t + 1) << 5);
    bf16x8 bfv = *reinterpret_cast<const bf16x8*>(&s_at[lrow * 1032 + (t << 5) + kt]);
    #pragma unroll
    for (int mi = 0; mi < 2; ++mi) {
      bf16x8 af = *reinterpret_cast<const bf16x8*>(&sA[cur][((w * 2 + mi) * 16 + lrow) * 32 + kt]);
      acc[mi] = __builtin_amdgcn_mfma_f32_16x16x32_bf16(af, bfv, acc[mi], 0, 0, 0);
    }
    cur ^= 1;
  }

  const int rb = (lane >> 4) << 2;
  const int s = lrow;
  #pragma unroll
  for (int mi = 0; mi < 2; ++mi) {
    int e0 = (et << 7) + (w * 2 + mi) * 16 + rb;
    ushort4 o;
    o.x = f2bf(acc[mi][0]); o.y = f2bf(acc[mi][1]);
    o.z = f2bf(acc[mi][2]); o.w = f2bf(acc[mi][3]);
    *reinterpret_cast<ushort4*>(&A2[(size_t)((b_ << 4) + s) * 1024 + e0]) = o;
  }
}

// ---------------- MFMA GEMM 64x64 (slot-sized GEMMs) ----------------

template<int BIAS, int RELU, int ADDSRC, int OUTBF16, int SCALE>
__global__ __launch_bounds__(256) void gemm_sm(
    const unsigned short* __restrict__ A, const unsigned short* __restrict__ W,
    const float* __restrict__ bias, const float* __restrict__ addsrc,
    void* __restrict__ Cout, int M, int N, int K, float scalev) {
  __shared__ unsigned short sA[2][2048];
  __shared__ unsigned short sB[2][2048];
  const int tid = threadIdx.x;
  const int lane = tid & 63, w = tid >> 6;

  int nwg = gridDim.x * gridDim.y;
  int flat = blockIdx.y * gridDim.x + blockIdx.x;
  if ((nwg & 7) == 0) { int c = nwg >> 3; flat = (flat & 7) * c + (flat >> 3); }
  const int row0 = (flat / gridDim.x) << 6;
  const int col0 = (flat % gridDim.x) << 6;

  const int lrow = lane & 15, kt = (lane >> 4) << 3;
  const int srow = lane >> 2, scol = (lane & 3) << 3;

  f32x4 acc[4];
  #pragma unroll
  for (int m = 0; m < 4; ++m) acc[m] = f32x4{0.f, 0.f, 0.f, 0.f};

  auto stage = [&](int buf, int k0) {
    int r = (w << 4) + srow;
    GLD16(A + (size_t)(row0 + r) * K + k0 + scol, &sA[buf][w * 512]);
    GLD16(W + (size_t)(col0 + r) * K + k0 + scol, &sB[buf][w * 512]);
  };

  stage(0, 0);
  const int nt = K >> 5;
  int cur = 0;
  for (int t = 0; t < nt; ++t) {
    __syncthreads();
    if (t + 1 < nt) stage(cur ^ 1, (t + 1) << 5);
    bf16x8 af[4], bfv;
    #pragma unroll
    for (int m = 0; m < 4; ++m)
      af[m] = *reinterpret_cast<const bf16x8*>(&sA[cur][(m * 16 + lrow) * 32 + kt]);
    bfv = *reinterpret_cast<const bf16x8*>(&sB[cur][((w << 4) + lrow) * 32 + kt]);
    #pragma unroll
    for (int m = 0; m < 4; ++m)
      acc[m] = __builtin_amdgcn_mfma_f32_16x16x32_bf16(af[m], bfv, acc[m], 0, 0, 0);
    cur ^= 1;
  }

  const int rb = (lane >> 4) << 2;
  const int col = col0 + (w << 4) + lrow;
  float bv = BIAS ? bias[col] : 0.0f;
  #pragma unroll
  for (int m = 0; m < 4; ++m) {
    #pragma unroll
    for (int r = 0; r < 4; ++r) {
      int row = row0 + m * 16 + rb + r;
      float v = acc[m][r];
      if (SCALE) v *= scalev;
      v += bv;
      if (ADDSRC) v += addsrc[(size_t)row * N + col];
      if (RELU) v = fmaxf(v, 0.0f);
      if (OUTBF16) ((unsigned short*)Cout)[(size_t)row * N + col] = f2bf(v);
      else ((float*)Cout)[(size_t)row * N + col] = v;
    }
  }
}

// ---------------- host launch ----------------

extern "C" void kernel_launch(void* const* d_in, const int* in_sizes, int n_in,
                              void* d_out, int out_size, void* d_ws, size_t ws_size,
                              hipStream_t stream) {
  const float* inputs  = (const float*)d_in[0];
  const float* noise   = (const float*)d_in[1];
  const float* slot_mu = (const float*)d_in[2];
  const float* slot_ls = (const float*)d_in[3];
  const float* ln_in_g = (const float*)d_in[4];
  const float* ln_in_b = (const float*)d_in[5];
  const float* ln_s_g  = (const float*)d_in[6];
  const float* ln_s_b  = (const float*)d_in[7];
  const float* ln_m_g  = (const float*)d_in[8];
  const float* ln_m_b  = (const float*)d_in[9];
  const float* Wq   = (const float*)d_in[10];
  const float* Wk   = (const float*)d_in[11];
  const float* Wv   = (const float*)d_in[12];
  const float* w_ih = (const float*)d_in[13];
  const float* w_hh = (const float*)d_in[14];
  const float* b_ih = (const float*)d_in[15];
  const float* b_hh = (const float*)d_in[16];
  const float* w1   = (const float*)d_in[17];
  const float* b1   = (const float*)d_in[18];
  const float* w2   = (const float*)d_in[19];
  const float* b2   = (const float*)d_in[20];

  const int BN = 65536, BS = 1024;

  uintptr_t base = (uintptr_t)d_ws;
  auto alloc = [&](size_t bytes) {
    void* p = (void*)base;
    base += (bytes + 255) & ~(size_t)255;
    return p;
  };
  unsigned short* x_bf    = (unsigned short*)alloc((size_t)BN * 512 * 2);
  unsigned short* xT      = (unsigned short*)alloc((size_t)64 * 512 * 1024 * 2);
  unsigned short* wqT     = (unsigned short*)alloc(512 * 512 * 2);
  unsigned short* wkT     = (unsigned short*)alloc(512 * 512 * 2);
  unsigned short* wvT     = (unsigned short*)alloc(512 * 512 * 2);
  unsigned short* wpt     = (unsigned short*)alloc(512 * 512 * 2);
  unsigned short* wih_bf  = (unsigned short*)alloc((size_t)1536 * 512 * 2);
  float*          wihp    = (float*)alloc((size_t)1536 * 512 * 4);
  unsigned short* wcat_bf = (unsigned short*)alloc((size_t)2048 * 1024 * 2);
  float*          bcat    = (float*)alloc(2048 * 4);
  unsigned short* w1_bf   = (unsigned short*)alloc(512 * 512 * 2);
  unsigned short* w2_bf   = (unsigned short*)alloc(512 * 512 * 2);
  float*          slots   = (float*)alloc((size_t)BS * 512 * 4);
  unsigned short* A2      = (unsigned short*)alloc((size_t)BS * 1024 * 2);
  unsigned short* q2_bf   = (unsigned short*)alloc((size_t)BS * 512 * 2);
  unsigned short* logits  = (unsigned short*)alloc((size_t)64 * 16 * 1024 * 2);
  float*          gates   = (float*)alloc((size_t)BS * 2048 * 4);
  float*          sgru    = (float*)alloc((size_t)BS * 512 * 4);
  unsigned short* lnm_bf  = (unsigned short*)alloc((size_t)BS * 512 * 2);
  unsigned short* h_bf    = (unsigned short*)alloc((size_t)BS * 512 * 2);
  (void)ws_size; (void)n_in; (void)in_sizes; (void)out_size;

  const float scale = 0.044194173824159216f;  // 512^-0.5

  // prologue
  wprep_k<<<7176, 256, 0, stream>>>(w1, w2, w_ih, b_ih, b_hh, slot_mu, slot_ls, noise,
                                    w1_bf, w2_bf, wih_bf, bcat, slots);
  tcast3_k<<<dim3(16, 16, 3), 256, 0, stream>>>(Wq, Wk, Wv, wqT, wkT, wvT);
  gemm_sm<0,0,0,1,1><<<dim3(8, 8), 256, 0, stream>>>(
      wkT, wqT, nullptr, nullptr, wpt, 512, 512, 512, scale);
  gemm_bt<0><<<dim3(4, 12), 256, 0, stream>>>(
      wih_bf, wvT, wihp, 1536, 512, 512);
  wcat_k<<<8192, 256, 0, stream>>>(wihp, w_hh, wcat_bf);
  ln_rows_k<<<16384, 256, 0, stream>>>(inputs, ln_in_g, ln_in_b, x_bf, BN);
  xt_k<<<dim3(16, 8, 64), 256, 0, stream>>>(x_bf, xT);

  for (int it = 0; it < 3; ++it) {
    q2ln_k<<<dim3(4, 64), 256, 0, stream>>>(slots, ln_s_g, ln_s_b, wpt, q2_bf, A2);
    logits_k<<<dim3(8, 64), 256, 0, stream>>>(q2_bf, x_bf, logits);
    pv_sm_k<<<dim3(4, 64), 256, 0, stream>>>(logits, xT, A2);
    gemm_sm<1,0,0,0,0><<<dim3(32, 16), 256, 0, stream>>>(
        A2, wcat_bf, bcat, nullptr, gates, BS, 2048, 1024, 1.0f);
    gru_ln_k<<<256, 256, 0, stream>>>(gates, slots, ln_m_g, ln_m_b, sgru, lnm_bf);
    gemm_sm<1,1,0,1,0><<<dim3(8, 16), 256, 0, stream>>>(
        lnm_bf, w1_bf, b1, nullptr, h_bf, BS, 512, 512, 1.0f);
    float* slots_out = (it == 2) ? (float*)d_out : slots;
    gemm_sm<1,0,1,0,0><<<dim3(8, 16), 256, 0, stream>>>(
        h_bf, w2_bf, b2, sgru, slots_out, BS, 512, 512, 1.0f);
  }
}

// Round 10
// 331.405 us; speedup vs baseline: 1.2249x; 1.0379x over previous
//
#include <hip/hip_runtime.h>
#include <hip/hip_bf16.h>
#include <cstdint>
#include <cstddef>

// Shapes fixed: B=64, N=1024, D=512, S=16, 3 iterations.
// Algebra: logits = sn·W'·x^T, W' = scale·Wq^T·Wk   (k never materialized)
//          ax = attn·x;  upd@Wih^T = ax@(Wih·Wv)^T  (v never materialized)
// This round: BK=64 (half the barrier-drained K-steps in all MFMA kernels),
//             wcat folded into the wihp GEMM epilogue.

typedef __bf16 bf16x8 __attribute__((ext_vector_type(8)));
typedef float f32x4 __attribute__((ext_vector_type(4)));

__device__ __forceinline__ float bf2f(unsigned int u) {
  union { unsigned int i; float f; } v; v.i = u << 16; return v.f;
}
__device__ __forceinline__ unsigned short f2bf(float x) {
  __hip_bfloat16 h = __float2bfloat16(x);
  unsigned short u;
  __builtin_memcpy(&u, &h, 2);
  return u;
}

#define GLD16(gp, lp)                                                       \
  __builtin_amdgcn_global_load_lds(                                         \
      (const __attribute__((address_space(1))) void*)(gp),                  \
      (__attribute__((address_space(3))) void*)(lp), 16, 0, 0)

// ---------------- merged prep (segmented grid) ----------------
// [0,1024)      w1 cast          [1024,2048)  w2 cast
// [2048,5120)   wih cast         [5120,7168)  wcat right rows[0,1024) <- whh[0,1024)
// [7168,8192)   wcat right rows[1536,2048) <- whh[1024,1536)
// [8192,10240)  wcat zeros (left rows[1536,2048), right rows[1024,1536))
// [10240,10248) bcat             [10248,12296) slots init

__global__ void wprep_k(const float* __restrict__ w1, const float* __restrict__ w2,
                        const float* __restrict__ wih, const float* __restrict__ whh,
                        const float* __restrict__ bih, const float* __restrict__ bhh,
                        const float* __restrict__ mu, const float* __restrict__ ls,
                        const float* __restrict__ noise,
                        unsigned short* __restrict__ w1_bf, unsigned short* __restrict__ w2_bf,
                        unsigned short* __restrict__ wih_bf, unsigned short* __restrict__ wcat,
                        float* __restrict__ bcat, float* __restrict__ slots) {
  int blk = blockIdx.x, t = threadIdx.x;
  if (blk < 1024) {
    int i = blk * 256 + t; w1_bf[i] = f2bf(w1[i]);
  } else if (blk < 2048) {
    int i = (blk - 1024) * 256 + t; w2_bf[i] = f2bf(w2[i]);
  } else if (blk < 5120) {
    int i = (blk - 2048) * 256 + t; wih_bf[i] = f2bf(wih[i]);
  } else if (blk < 7168) {
    int i = (blk - 5120) * 256 + t;  // 524288: rows 0..1024 right half
    int j = i >> 9, d = i & 511;
    wcat[(size_t)j * 1024 + 512 + d] = f2bf(whh[(size_t)j * 512 + d]);
  } else if (blk < 8192) {
    int i = (blk - 7168) * 256 + t;  // 262144: rows 1536..2048 right half
    int j = i >> 9, d = i & 511;
    wcat[(size_t)(1536 + j) * 1024 + 512 + d] = f2bf(whh[(size_t)(1024 + j) * 512 + d]);
  } else if (blk < 10240) {
    int i = (blk - 8192) * 256 + t;  // 524288 zeros
    if (i < 262144) {
      int j = i >> 9, d = i & 511;
      wcat[(size_t)(1536 + j) * 1024 + d] = 0;         // left rows[1536,2048)
    } else {
      int k = i - 262144;
      int j = k >> 9, d = k & 511;
      wcat[(size_t)(1024 + j) * 1024 + 512 + d] = 0;   // right rows[1024,1536)
    }
  } else if (blk < 10248) {
    int j = (blk - 10240) * 256 + t;  // 2048
    float v;
    if (j < 1024)      v = bih[j] + bhh[j];
    else if (j < 1536) v = bih[j];
    else               v = bhh[j - 512];
    bcat[j] = v;
  } else {
    int i = (blk - 10248) * 256 + t;  // 524288
    int d = i & 511;
    slots[i] = mu[d] + expf(ls[d]) * noise[i];
  }
}

// transpose + cast Wq, Wk, Wv: grid (16,16,3)
__global__ __launch_bounds__(256) void tcast3_k(const float* __restrict__ Wq,
                                                const float* __restrict__ Wk,
                                                const float* __restrict__ Wv,
                                                unsigned short* __restrict__ wqT,
                                                unsigned short* __restrict__ wkT,
                                                unsigned short* __restrict__ wvT) {
  __shared__ float tt[32][33];
  const float* in = blockIdx.z == 0 ? Wq : (blockIdx.z == 1 ? Wk : Wv);
  unsigned short* out = blockIdx.z == 0 ? wqT : (blockIdx.z == 1 ? wkT : wvT);
  int c0 = blockIdx.x << 5, r0 = blockIdx.y << 5;
  int tx = threadIdx.x & 31, ty = threadIdx.x >> 5;
  #pragma unroll
  for (int i = 0; i < 4; ++i)
    tt[ty + 8 * i][tx] = in[(size_t)(r0 + ty + 8 * i) * 512 + c0 + tx];
  __syncthreads();
  #pragma unroll
  for (int i = 0; i < 4; ++i)
    out[(size_t)(c0 + ty + 8 * i) * 512 + r0 + tx] = f2bf(tt[tx][ty + 8 * i]);
}

// ---------------- layernorm inputs (wave per row, D=512) ----------------

__global__ __launch_bounds__(256) void ln_rows_k(
    const float* __restrict__ in, const float* __restrict__ g, const float* __restrict__ b,
    unsigned short* __restrict__ out, int rows) {
  int w = threadIdx.x >> 6, lane = threadIdx.x & 63;
  int row = (blockIdx.x << 2) + w;
  if (row >= rows) return;
  const float4* rp = reinterpret_cast<const float4*>(in + (size_t)row * 512);
  float4 v0 = rp[lane], v1 = rp[lane + 64];
  float s = v0.x + v0.y + v0.z + v0.w + v1.x + v1.y + v1.z + v1.w;
  float q = v0.x*v0.x + v0.y*v0.y + v0.z*v0.z + v0.w*v0.w
          + v1.x*v1.x + v1.y*v1.y + v1.z*v1.z + v1.w*v1.w;
  #pragma unroll
  for (int o = 32; o > 0; o >>= 1) { s += __shfl_xor(s, o); q += __shfl_xor(q, o); }
  float m = s * (1.0f / 512.0f);
  float rstd = rsqrtf(q * (1.0f / 512.0f) - m * m + 1e-8f);
  const float4* gp = reinterpret_cast<const float4*>(g);
  const float4* bp = reinterpret_cast<const float4*>(b);
  float4 g0 = gp[lane], g1 = gp[lane + 64];
  float4 b0 = bp[lane], b1 = bp[lane + 64];
  ushort4 o0, o1;
  o0.x = f2bf((v0.x - m) * rstd * g0.x + b0.x);
  o0.y = f2bf((v0.y - m) * rstd * g0.y + b0.y);
  o0.z = f2bf((v0.z - m) * rstd * g0.z + b0.z);
  o0.w = f2bf((v0.w - m) * rstd * g0.w + b0.w);
  o1.x = f2bf((v1.x - m) * rstd * g1.x + b1.x);
  o1.y = f2bf((v1.y - m) * rstd * g1.y + b1.y);
  o1.z = f2bf((v1.z - m) * rstd * g1.z + b1.z);
  o1.w = f2bf((v1.w - m) * rstd * g1.w + b1.w);
  ushort4* op = reinterpret_cast<ushort4*>(out + (size_t)row * 512);
  op[lane] = o0; op[lane + 64] = o1;
}

// ---------------- xT[b][e][n] = x_bf[b*1024+n][e] ----------------

__global__ __launch_bounds__(256) void xt_k(const unsigned short* __restrict__ x,
                                            unsigned short* __restrict__ xT) {
  __shared__ unsigned short t[64][68];
  int nt = blockIdx.x, et = blockIdx.y, b = blockIdx.z;
  int r = threadIdx.x >> 3, c8 = (threadIdx.x & 7) << 3;
  #pragma unroll
  for (int p = 0; p < 2; ++p) {
    int row = r + (p << 5);
    *reinterpret_cast<uint4*>(&t[row][c8]) = *reinterpret_cast<const uint4*>(
        x + ((size_t)(b << 10) + (nt << 6) + row) * 512 + (et << 6) + c8);
  }
  __syncthreads();
  #pragma unroll
  for (int p = 0; p < 2; ++p) {
    int erow = r + (p << 5);
    ushort4 a, bb;
    #pragma unroll
    for (int j = 0; j < 4; ++j) ((unsigned short*)&a)[j] = t[c8 + j][erow];
    #pragma unroll
    for (int j = 0; j < 4; ++j) ((unsigned short*)&bb)[j] = t[c8 + 4 + j][erow];
    unsigned short* o = xT + ((size_t)(b << 9) + (et << 6) + erow) * 1024 + (nt << 6) + c8;
    *reinterpret_cast<ushort4*>(o) = a;
    *reinterpret_cast<ushort4*>(o + 4) = bb;
  }
}

// GRU (fused-gates layout) + LN
__global__ __launch_bounds__(256) void gru_ln_k(
    const float* __restrict__ gates, const float* __restrict__ hp,
    const float* __restrict__ g, const float* __restrict__ b,
    float* __restrict__ sgru, unsigned short* __restrict__ lnm) {
  int w = threadIdx.x >> 6, lane = threadIdx.x & 63;
  int row = (blockIdx.x << 2) + w;
  size_t gb = (size_t)row * 2048 + (lane << 3);
  size_t hb = (size_t)row * 512 + (lane << 3);
  float rs[8], zs[8], in_[8], hn[8], hv[8], y[8];
  #pragma unroll
  for (int c = 0; c < 2; ++c) {
    *reinterpret_cast<float4*>(rs + 4*c)  = *reinterpret_cast<const float4*>(gates + gb + 4*c);
    *reinterpret_cast<float4*>(zs + 4*c)  = *reinterpret_cast<const float4*>(gates + gb + 512 + 4*c);
    *reinterpret_cast<float4*>(in_ + 4*c) = *reinterpret_cast<const float4*>(gates + gb + 1024 + 4*c);
    *reinterpret_cast<float4*>(hn + 4*c)  = *reinterpret_cast<const float4*>(gates + gb + 1536 + 4*c);
    *reinterpret_cast<float4*>(hv + 4*c)  = *reinterpret_cast<const float4*>(hp + hb + 4*c);
  }
  float s = 0.f, q = 0.f;
  #pragma unroll
  for (int j = 0; j < 8; ++j) {
    float r = 1.0f / (1.0f + expf(-rs[j]));
    float z = 1.0f / (1.0f + expf(-zs[j]));
    float n = tanhf(in_[j] + r * hn[j]);
    float h = (1.0f - z) * n + z * hv[j];
    y[j] = h; s += h; q += h * h;
  }
  #pragma unroll
  for (int o = 32; o > 0; o >>= 1) { s += __shfl_xor(s, o); q += __shfl_xor(q, o); }
  float m = s * (1.0f / 512.0f);
  float rstd = rsqrtf(q * (1.0f / 512.0f) - m * m + 1e-8f);
  const float* gg = g + (lane << 3);
  const float* bb = b + (lane << 3);
  #pragma unroll
  for (int c = 0; c < 2; ++c)
    *reinterpret_cast<float4*>(sgru + hb + 4*c) = *reinterpret_cast<const float4*>(y + 4*c);
  uint4 o4;
  unsigned int p[8];
  #pragma unroll
  for (int j = 0; j < 8; ++j) p[j] = f2bf((y[j] - m) * rstd * gg[j] + bb[j]);
  o4.x = p[0] | (p[1] << 16); o4.y = p[2] | (p[3] << 16);
  o4.z = p[4] | (p[5] << 16); o4.w = p[6] | (p[7] << 16);
  *reinterpret_cast<uint4*>(lnm + hb) = o4;
}

// ---------------- gemm_cat: wcat[j][0..512) = bf16(wih @ Wv), ldc=1024, BK=64 ----------------
// 128x128 tile, grid (4,12). M=1536, N=512, K=512.

__global__ __launch_bounds__(256) void gemm_cat(
    const unsigned short* __restrict__ A, const unsigned short* __restrict__ W,
    unsigned short* __restrict__ Cout, int M, int N, int K, int ldc) {
  __shared__ unsigned short sA[2][8192];  // [128][64]
  __shared__ unsigned short sB[2][8192];
  const int tid = threadIdx.x;
  const int lane = tid & 63, w = tid >> 6;

  int nwg = gridDim.x * gridDim.y;
  int flat = blockIdx.y * gridDim.x + blockIdx.x;
  if ((nwg & 7) == 0) { int c = nwg >> 3; flat = (flat & 7) * c + (flat >> 3); }
  const int row0 = (flat / gridDim.x) << 7;
  const int col0 = (flat % gridDim.x) << 7;

  const int wm = (w >> 1) << 6, wn = (w & 1) << 6;
  const int lrow = lane & 15, kt = (lane >> 4) << 3;
  const int sr8 = lane >> 3, sc8 = (lane & 7) << 3;

  f32x4 acc[4][4];
  #pragma unroll
  for (int m = 0; m < 4; ++m)
    #pragma unroll
    for (int n = 0; n < 4; ++n) acc[m][n] = f32x4{0.f, 0.f, 0.f, 0.f};

  auto stage = [&](int buf, int k0) {
    #pragma unroll
    for (int i = 0; i < 4; ++i) {
      int ii = (w << 2) + i;
      int r = (ii << 3) + sr8;
      GLD16(A + (size_t)(row0 + r) * K + k0 + sc8, &sA[buf][ii * 512]);
      GLD16(W + (size_t)(col0 + r) * K + k0 + sc8, &sB[buf][ii * 512]);
    }
  };

  stage(0, 0);
  const int nt = K >> 6;
  int cur = 0;
  for (int t = 0; t < nt; ++t) {
    __syncthreads();
    if (t + 1 < nt) stage(cur ^ 1, (t + 1) << 6);
    #pragma unroll
    for (int kk = 0; kk < 2; ++kk) {
      bf16x8 af[4], bfv[4];
      #pragma unroll
      for (int m = 0; m < 4; ++m)
        af[m] = *reinterpret_cast<const bf16x8*>(&sA[cur][(wm + m * 16 + lrow) * 64 + (kk << 5) + kt]);
      #pragma unroll
      for (int n = 0; n < 4; ++n)
        bfv[n] = *reinterpret_cast<const bf16x8*>(&sB[cur][(wn + n * 16 + lrow) * 64 + (kk << 5) + kt]);
      #pragma unroll
      for (int m = 0; m < 4; ++m)
        #pragma unroll
        for (int n = 0; n < 4; ++n)
          acc[m][n] = __builtin_amdgcn_mfma_f32_16x16x32_bf16(af[m], bfv[n], acc[m][n], 0, 0, 0);
    }
    cur ^= 1;
  }

  const int rb = (lane >> 4) << 2;
  #pragma unroll
  for (int m = 0; m < 4; ++m) {
    #pragma unroll
    for (int n = 0; n < 4; ++n) {
      int col = col0 + wn + n * 16 + lrow;
      #pragma unroll
      for (int r = 0; r < 4; ++r) {
        int row = row0 + wm + m * 16 + rb + r;
        Cout[(size_t)row * ldc + col] = f2bf(acc[m][n][r]);
      }
    }
  }
}

// ---------------- q2ln: LN(slots_b) in LDS, then q2 = sn @ W' tile (BK=64) ----------------

__global__ __launch_bounds__(256) void q2ln_k(
    const float* __restrict__ slots, const float* __restrict__ g, const float* __restrict__ b,
    const unsigned short* __restrict__ wpt, unsigned short* __restrict__ q2,
    unsigned short* __restrict__ A2) {
  __shared__ unsigned short s_sn[16 * 520];
  __shared__ unsigned short sB[2][8192];  // [128][64]
  const int b_ = blockIdx.y, ct = blockIdx.x;
  const int lane = threadIdx.x & 63, w = threadIdx.x >> 6;
  const int lrow = lane & 15, kt = (lane >> 4) << 3;
  const int sr8 = lane >> 3, sc8 = (lane & 7) << 3;

  const float4* gp = reinterpret_cast<const float4*>(g);
  const float4* bp = reinterpret_cast<const float4*>(b);
  float4 g0 = gp[lane], g1 = gp[lane + 64];
  float4 b0 = bp[lane], b1 = bp[lane + 64];
  #pragma unroll
  for (int rr = 0; rr < 4; ++rr) {
    int r = w * 4 + rr;
    const float4* rp = reinterpret_cast<const float4*>(slots + (size_t)(b_ * 16 + r) * 512);
    float4 v0 = rp[lane], v1 = rp[lane + 64];
    float s = v0.x + v0.y + v0.z + v0.w + v1.x + v1.y + v1.z + v1.w;
    float q = v0.x*v0.x + v0.y*v0.y + v0.z*v0.z + v0.w*v0.w
            + v1.x*v1.x + v1.y*v1.y + v1.z*v1.z + v1.w*v1.w;
    #pragma unroll
    for (int o = 32; o > 0; o >>= 1) { s += __shfl_xor(s, o); q += __shfl_xor(q, o); }
    float m = s * (1.0f / 512.0f);
    float rstd = rsqrtf(q * (1.0f / 512.0f) - m * m + 1e-8f);
    ushort4 o0, o1;
    o0.x = f2bf((v0.x - m) * rstd * g0.x + b0.x);
    o0.y = f2bf((v0.y - m) * rstd * g0.y + b0.y);
    o0.z = f2bf((v0.z - m) * rstd * g0.z + b0.z);
    o0.w = f2bf((v0.w - m) * rstd * g0.w + b0.w);
    o1.x = f2bf((v1.x - m) * rstd * g1.x + b1.x);
    o1.y = f2bf((v1.y - m) * rstd * g1.y + b1.y);
    o1.z = f2bf((v1.z - m) * rstd * g1.z + b1.z);
    o1.w = f2bf((v1.w - m) * rstd * g1.w + b1.w);
    *reinterpret_cast<ushort4*>(&s_sn[r * 520 + lane * 4]) = o0;
    *reinterpret_cast<ushort4*>(&s_sn[r * 520 + 256 + lane * 4]) = o1;
    if (ct == 0) {
      ushort4 c0, c1;
      c0.x = f2bf(v0.x); c0.y = f2bf(v0.y); c0.z = f2bf(v0.z); c0.w = f2bf(v0.w);
      c1.x = f2bf(v1.x); c1.y = f2bf(v1.y); c1.z = f2bf(v1.z); c1.w = f2bf(v1.w);
      unsigned short* a2r = A2 + (size_t)(b_ * 16 + r) * 1024 + 512;
      *reinterpret_cast<ushort4*>(a2r + lane * 4) = c0;
      *reinterpret_cast<ushort4*>(a2r + 256 + lane * 4) = c1;
    }
  }

  const unsigned short* Bb = wpt + (size_t)(ct << 7) * 512;
  auto stage = [&](int buf, int k0) {
    #pragma unroll
    for (int i = 0; i < 4; ++i) {
      int ii = (w << 2) + i;
      GLD16(Bb + (size_t)((ii << 3) + sr8) * 512 + k0 + sc8, &sB[buf][ii * 512]);
    }
  };

  f32x4 acc[2];
  acc[0] = f32x4{0.f, 0.f, 0.f, 0.f};
  acc[1] = f32x4{0.f, 0.f, 0.f, 0.f};

  stage(0, 0);
  int cur = 0;
  for (int t = 0; t < 8; ++t) {
    __syncthreads();
    if (t + 1 < 8) stage(cur ^ 1, (t + 1) << 6);
    #pragma unroll
    for (int kk = 0; kk < 2; ++kk) {
      bf16x8 af = *reinterpret_cast<const bf16x8*>(&s_sn[lrow * 520 + (t << 6) + (kk << 5) + kt]);
      #pragma unroll
      for (int ni = 0; ni < 2; ++ni) {
        bf16x8 bfv = *reinterpret_cast<const bf16x8*>(
            &sB[cur][((w * 2 + ni) * 16 + lrow) * 64 + (kk << 5) + kt]);
        acc[ni] = __builtin_amdgcn_mfma_f32_16x16x32_bf16(af, bfv, acc[ni], 0, 0, 0);
      }
    }
    cur ^= 1;
  }

  const int rb = (lane >> 4) << 2;
  #pragma unroll
  for (int ni = 0; ni < 2; ++ni) {
    int col = (ct << 7) + (w * 2 + ni) * 16 + lrow;
    #pragma unroll
    for (int r = 0; r < 4; ++r) {
      int s = rb + r;
      q2[(size_t)((b_ << 4) + s) * 512 + col] = f2bf(acc[ni][r]);
    }
  }
}

// ---------------- logits[b][16][1024] = q2_b @ x_b^T  (bf16 out, BK=64) ----------------

__global__ __launch_bounds__(256) void logits_k(
    const unsigned short* __restrict__ q2, const unsigned short* __restrict__ x,
    unsigned short* __restrict__ out) {
  __shared__ unsigned short sA[2][1024];  // [16][64]
  __shared__ unsigned short sB[2][8192];  // [128][64]
  const int b = blockIdx.y, nt = blockIdx.x;
  const int lane = threadIdx.x & 63, w = threadIdx.x >> 6;
  const int lrow = lane & 15, kt = (lane >> 4) << 3;
  const int sr8 = lane >> 3, sc8 = (lane & 7) << 3;
  const unsigned short* Ab = q2 + ((size_t)b << 13);
  const unsigned short* Bb = x + (((size_t)(b << 10) + (nt << 7)) << 9);

  f32x4 acc[2];
  acc[0] = f32x4{0.f, 0.f, 0.f, 0.f};
  acc[1] = f32x4{0.f, 0.f, 0.f, 0.f};

  auto stage = [&](int buf, int k0) {
    #pragma unroll
    for (int i = 0; i < 4; ++i) {
      int ii = (w << 2) + i;
      GLD16(Bb + (size_t)((ii << 3) + sr8) * 512 + k0 + sc8, &sB[buf][ii * 512]);
    }
    if (w == 0) {
      #pragma unroll
      for (int i = 0; i < 2; ++i)
        GLD16(Ab + (size_t)((i << 3) + sr8) * 512 + k0 + sc8, &sA[buf][i * 512]);
    }
  };

  stage(0, 0);
  int cur = 0;
  for (int t = 0; t < 8; ++t) {
    __syncthreads();
    if (t + 1 < 8) stage(cur ^ 1, (t + 1) << 6);
    #pragma unroll
    for (int kk = 0; kk < 2; ++kk) {
      bf16x8 af = *reinterpret_cast<const bf16x8*>(&sA[cur][lrow * 64 + (kk << 5) + kt]);
      #pragma unroll
      for (int ni = 0; ni < 2; ++ni) {
        bf16x8 bfv = *reinterpret_cast<const bf16x8*>(
            &sB[cur][((w * 2 + ni) * 16 + lrow) * 64 + (kk << 5) + kt]);
        acc[ni] = __builtin_amdgcn_mfma_f32_16x16x32_bf16(af, bfv, acc[ni], 0, 0, 0);
      }
    }
    cur ^= 1;
  }

  const int rb = (lane >> 4) << 2;
  #pragma unroll
  for (int ni = 0; ni < 2; ++ni) {
    int n = (nt << 7) + (w * 2 + ni) * 16 + lrow;
    #pragma unroll
    for (int r = 0; r < 4; ++r) {
      int s = rb + r;
      out[(size_t)((b << 4) + s) * 1024 + n] = f2bf(acc[ni][r]);
    }
  }
}

// ---------------- pv_sm: softmax+colnorm (LDS attn) + ax MFMA vs xT (BK=64) ----------------
// grid (4 e-tiles, 64 b), block 256.

__global__ __launch_bounds__(256) void pv_sm_k(
    const unsigned short* __restrict__ logits, const unsigned short* __restrict__ xT,
    unsigned short* __restrict__ A2) {
  __shared__ float s_mi[16][2];
  __shared__ unsigned short s_at[16 * 1032];
  __shared__ unsigned short sA[2][8192];  // [128 e][64 n]
  const int b_ = blockIdx.y, et = blockIdx.x;
  const int lane = threadIdx.x & 63, w = threadIdx.x >> 6;
  const int lrow = lane & 15, kt = (lane >> 4) << 3;
  const int sr8 = lane >> 3, sc8 = (lane & 7) << 3;
  const unsigned short* lg = logits + ((size_t)b_ << 14);

  // phase 1: row softmax stats
  #pragma unroll
  for (int rr = 0; rr < 4; ++rr) {
    int r = w * 4 + rr;
    const unsigned short* rp = lg + (size_t)r * 1024;
    float v[16];
    float mx = -3.4e38f;
    #pragma unroll
    for (int i = 0; i < 16; ++i) { v[i] = bf2f(rp[lane + (i << 6)]); mx = fmaxf(mx, v[i]); }
    #pragma unroll
    for (int o = 32; o > 0; o >>= 1) mx = fmaxf(mx, __shfl_xor(mx, o));
    float s = 0.f;
    #pragma unroll
    for (int i = 0; i < 16; ++i) s += __expf(v[i] - mx);
    #pragma unroll
    for (int o = 32; o > 0; o >>= 1) s += __shfl_xor(s, o);
    if (lane == 0) { s_mi[r][0] = mx; s_mi[r][1] = 1.0f / s; }
  }
  __syncthreads();

  // phase 2: column norm -> LDS bf16
  #pragma unroll
  for (int j = 0; j < 4; ++j) {
    int c = threadIdx.x + (j << 8);
    float e[16];
    float cs = 0.f;
    #pragma unroll
    for (int s = 0; s < 16; ++s) {
      e[s] = __expf(bf2f(lg[(size_t)s * 1024 + c]) - s_mi[s][0]) * s_mi[s][1];
      cs += e[s];
    }
    float rv = 1.0f / (cs + 1e-8f);
    #pragma unroll
    for (int s = 0; s < 16; ++s) s_at[s * 1032 + c] = f2bf(e[s] * rv);
  }

  // phase 3: ax^T via MFMA (A = xT stripe, B = attn from LDS)
  const unsigned short* Ab = xT + ((size_t)b_ << 19) + (size_t)(et << 7) * 1024;
  auto stage = [&](int buf, int k0) {
    #pragma unroll
    for (int i = 0; i < 4; ++i) {
      int ii = (w << 2) + i;
      GLD16(Ab + (size_t)((ii << 3) + sr8) * 1024 + k0 + sc8, &sA[buf][ii * 512]);
    }
  };

  f32x4 acc[2];
  acc[0] = f32x4{0.f, 0.f, 0.f, 0.f};
  acc[1] = f32x4{0.f, 0.f, 0.f, 0.f};

  stage(0, 0);
  int cur = 0;
  for (int t = 0; t < 16; ++t) {
    __syncthreads();
    if (t + 1 < 16) stage(cur ^ 1, (t + 1) << 6);
    #pragma unroll
    for (int kk = 0; kk < 2; ++kk) {
      bf16x8 bfv = *reinterpret_cast<const bf16x8*>(&s_at[lrow * 1032 + (t << 6) + (kk << 5) + kt]);
      #pragma unroll
      for (int mi = 0; mi < 2; ++mi) {
        bf16x8 af = *reinterpret_cast<const bf16x8*>(
            &sA[cur][((w * 2 + mi) * 16 + lrow) * 64 + (kk << 5) + kt]);
        acc[mi] = __builtin_amdgcn_mfma_f32_16x16x32_bf16(af, bfv, acc[mi], 0, 0, 0);
      }
    }
    cur ^= 1;
  }

  const int rb = (lane >> 4) << 2;
  const int s = lrow;
  #pragma unroll
  for (int mi = 0; mi < 2; ++mi) {
    int e0 = (et << 7) + (w * 2 + mi) * 16 + rb;
    ushort4 o;
    o.x = f2bf(acc[mi][0]); o.y = f2bf(acc[mi][1]);
    o.z = f2bf(acc[mi][2]); o.w = f2bf(acc[mi][3]);
    *reinterpret_cast<ushort4*>(&A2[(size_t)((b_ << 4) + s) * 1024 + e0]) = o;
  }
}

// ---------------- MFMA GEMM 64x64 (slot-sized GEMMs, BK=64) ----------------

template<int BIAS, int RELU, int ADDSRC, int OUTBF16, int SCALE>
__global__ __launch_bounds__(256) void gemm_sm(
    const unsigned short* __restrict__ A, const unsigned short* __restrict__ W,
    const float* __restrict__ bias, const float* __restrict__ addsrc,
    void* __restrict__ Cout, int M, int N, int K, float scalev) {
  __shared__ unsigned short sA[2][4096];  // [64][64]
  __shared__ unsigned short sB[2][4096];
  const int tid = threadIdx.x;
  const int lane = tid & 63, w = tid >> 6;

  int nwg = gridDim.x * gridDim.y;
  int flat = blockIdx.y * gridDim.x + blockIdx.x;
  if ((nwg & 7) == 0) { int c = nwg >> 3; flat = (flat & 7) * c + (flat >> 3); }
  const int row0 = (flat / gridDim.x) << 6;
  const int col0 = (flat % gridDim.x) << 6;

  const int lrow = lane & 15, kt = (lane >> 4) << 3;
  const int sr8 = lane >> 3, sc8 = (lane & 7) << 3;

  f32x4 acc[4];
  #pragma unroll
  for (int m = 0; m < 4; ++m) acc[m] = f32x4{0.f, 0.f, 0.f, 0.f};

  auto stage = [&](int buf, int k0) {
    #pragma unroll
    for (int i = 0; i < 2; ++i) {
      int ii = (w << 1) + i;
      int r = (ii << 3) + sr8;
      GLD16(A + (size_t)(row0 + r) * K + k0 + sc8, &sA[buf][ii * 512]);
      GLD16(W + (size_t)(col0 + r) * K + k0 + sc8, &sB[buf][ii * 512]);
    }
  };

  stage(0, 0);
  const int nt = K >> 6;
  int cur = 0;
  for (int t = 0; t < nt; ++t) {
    __syncthreads();
    if (t + 1 < nt) stage(cur ^ 1, (t + 1) << 6);
    #pragma unroll
    for (int kk = 0; kk < 2; ++kk) {
      bf16x8 bfv = *reinterpret_cast<const bf16x8*>(
          &sB[cur][((w << 4) + lrow) * 64 + (kk << 5) + kt]);
      #pragma unroll
      for (int m = 0; m < 4; ++m) {
        bf16x8 af = *reinterpret_cast<const bf16x8*>(
            &sA[cur][(m * 16 + lrow) * 64 + (kk << 5) + kt]);
        acc[m] = __builtin_amdgcn_mfma_f32_16x16x32_bf16(af, bfv, acc[m], 0, 0, 0);
      }
    }
    cur ^= 1;
  }

  const int rb = (lane >> 4) << 2;
  const int col = col0 + (w << 4) + lrow;
  float bv = BIAS ? bias[col] : 0.0f;
  #pragma unroll
  for (int m = 0; m < 4; ++m) {
    #pragma unroll
    for (int r = 0; r < 4; ++r) {
      int row = row0 + m * 16 + rb + r;
      float v = acc[m][r];
      if (SCALE) v *= scalev;
      v += bv;
      if (ADDSRC) v += addsrc[(size_t)row * N + col];
      if (RELU) v = fmaxf(v, 0.0f);
      if (OUTBF16) ((unsigned short*)Cout)[(size_t)row * N + col] = f2bf(v);
      else ((float*)Cout)[(size_t)row * N + col] = v;
    }
  }
}

// ---------------- host launch ----------------

extern "C" void kernel_launch(void* const* d_in, const int* in_sizes, int n_in,
                              void* d_out, int out_size, void* d_ws, size_t ws_size,
                              hipStream_t stream) {
  const float* inputs  = (const float*)d_in[0];
  const float* noise   = (const float*)d_in[1];
  const float* slot_mu = (const float*)d_in[2];
  const float* slot_ls = (const float*)d_in[3];
  const float* ln_in_g = (const float*)d_in[4];
  const float* ln_in_b = (const float*)d_in[5];
  const float* ln_s_g  = (const float*)d_in[6];
  const float* ln_s_b  = (const float*)d_in[7];
  const float* ln_m_g  = (const float*)d_in[8];
  const float* ln_m_b  = (const float*)d_in[9];
  const float* Wq   = (const float*)d_in[10];
  const float* Wk   = (const float*)d_in[11];
  const float* Wv   = (const float*)d_in[12];
  const float* w_ih = (const float*)d_in[13];
  const float* w_hh = (const float*)d_in[14];
  const float* b_ih = (const float*)d_in[15];
  const float* b_hh = (const float*)d_in[16];
  const float* w1   = (const float*)d_in[17];
  const float* b1   = (const float*)d_in[18];
  const float* w2   = (const float*)d_in[19];
  const float* b2   = (const float*)d_in[20];

  const int BN = 65536, BS = 1024;

  uintptr_t base = (uintptr_t)d_ws;
  auto alloc = [&](size_t bytes) {
    void* p = (void*)base;
    base += (bytes + 255) & ~(size_t)255;
    return p;
  };
  unsigned short* x_bf    = (unsigned short*)alloc((size_t)BN * 512 * 2);
  unsigned short* xT      = (unsigned short*)alloc((size_t)64 * 512 * 1024 * 2);
  unsigned short* wqT     = (unsigned short*)alloc(512 * 512 * 2);
  unsigned short* wkT     = (unsigned short*)alloc(512 * 512 * 2);
  unsigned short* wvT     = (unsigned short*)alloc(512 * 512 * 2);
  unsigned short* wpt     = (unsigned short*)alloc(512 * 512 * 2);
  unsigned short* wih_bf  = (unsigned short*)alloc((size_t)1536 * 512 * 2);
  unsigned short* wcat_bf = (unsigned short*)alloc((size_t)2048 * 1024 * 2);
  float*          bcat    = (float*)alloc(2048 * 4);
  unsigned short* w1_bf   = (unsigned short*)alloc(512 * 512 * 2);
  unsigned short* w2_bf   = (unsigned short*)alloc(512 * 512 * 2);
  float*          slots   = (float*)alloc((size_t)BS * 512 * 4);
  unsigned short* A2      = (unsigned short*)alloc((size_t)BS * 1024 * 2);
  unsigned short* q2_bf   = (unsigned short*)alloc((size_t)BS * 512 * 2);
  unsigned short* logits  = (unsigned short*)alloc((size_t)64 * 16 * 1024 * 2);
  float*          gates   = (float*)alloc((size_t)BS * 2048 * 4);
  float*          sgru    = (float*)alloc((size_t)BS * 512 * 4);
  unsigned short* lnm_bf  = (unsigned short*)alloc((size_t)BS * 512 * 2);
  unsigned short* h_bf    = (unsigned short*)alloc((size_t)BS * 512 * 2);
  (void)ws_size; (void)n_in; (void)in_sizes; (void)out_size;

  const float scale = 0.044194173824159216f;  // 512^-0.5

  // prologue (6 dispatches)
  wprep_k<<<12296, 256, 0, stream>>>(w1, w2, w_ih, w_hh, b_ih, b_hh,
                                     slot_mu, slot_ls, noise,
                                     w1_bf, w2_bf, wih_bf, wcat_bf, bcat, slots);
  tcast3_k<<<dim3(16, 16, 3), 256, 0, stream>>>(Wq, Wk, Wv, wqT, wkT, wvT);
  gemm_sm<0,0,0,1,1><<<dim3(8, 8), 256, 0, stream>>>(
      wkT, wqT, nullptr, nullptr, wpt, 512, 512, 512, scale);
  gemm_cat<<<dim3(4, 12), 256, 0, stream>>>(
      wih_bf, wvT, wcat_bf, 1536, 512, 512, 1024);
  ln_rows_k<<<16384, 256, 0, stream>>>(inputs, ln_in_g, ln_in_b, x_bf, BN);
  xt_k<<<dim3(16, 8, 64), 256, 0, stream>>>(x_bf, xT);

  for (int it = 0; it < 3; ++it) {
    q2ln_k<<<dim3(4, 64), 256, 0, stream>>>(slots, ln_s_g, ln_s_b, wpt, q2_bf, A2);
    logits_k<<<dim3(8, 64), 256, 0, stream>>>(q2_bf, x_bf, logits);
    pv_sm_k<<<dim3(4, 64), 256, 0, stream>>>(logits, xT, A2);
    gemm_sm<1,0,0,0,0><<<dim3(32, 16), 256, 0, stream>>>(
        A2, wcat_bf, bcat, nullptr, gates, BS, 2048, 1024, 1.0f);
    gru_ln_k<<<256, 256, 0, stream>>>(gates, slots, ln_m_g, ln_m_b, sgru, lnm_bf);
    gemm_sm<1,1,0,1,0><<<dim3(8, 16), 256, 0, stream>>>(
        lnm_bf, w1_bf, b1, nullptr, h_bf, BS, 512, 512, 1.0f);
    float* slots_out = (it == 2) ? (float*)d_out : slots;
    gemm_sm<1,0,1,0,0><<<dim3(8, 16), 256, 0, stream>>>(
        h_bf, w2_bf, b2, sgru, slots_out, BS, 512, 512, 1.0f);
  }
}